// Round 14
// baseline (251.784 us; speedup 1.0000x reference)
//
#include <hip/hip_runtime.h>
#include <hip/hip_bf16.h>

typedef __attribute__((ext_vector_type(8))) short short8;
typedef __attribute__((ext_vector_type(4))) short short4v;
typedef __attribute__((ext_vector_type(4))) float floatx4;

__device__ __forceinline__ void gload_lds16(const void* g, void* l) {
  __builtin_amdgcn_global_load_lds(
      (const __attribute__((address_space(1))) void*)g,
      (__attribute__((address_space(3))) void*)l, 16, 0, 0);
}

// tanh-approx GELU via sigmoid; branch-free (v_exp + v_rcp)
__device__ __forceinline__ float gelu_fast(float x) {
  float z = 1.5957691216f * (x + 0.044715f * x * x * x);
  float e = __expf(-z);
  return x * __builtin_amdgcn_rcpf(1.0f + e);
}

#define FENCE() asm volatile("" ::: "memory")

// ================= 256x256x(K=512) counted-vmcnt NT GEMM =================
// C[M,512] = epi(A[M,512] @ B[512,512]^T + bias); 512 thr (8 waves, 2x4),
// per-wave out 128x64, BK=64, dbuf LDS 128KB.
// T2 swizzle via pre-swizzled global source; T4 counted-vmcnt pipeline.
// SWZ=1: chunked XCD (grid total must be 256). SWZ=2: P-grid (2,2,64).
template<bool GELU_OUT, bool HASBIAS, bool OUT_F32, int SWZ>
__device__ __forceinline__
void gemm256_body(const __hip_bfloat16* __restrict__ Ag,
                  const __hip_bfloat16* __restrict__ Bg,
                  const float* __restrict__ bias,
                  void* __restrict__ Cg,
                  long sA, long sB, long sC)
{
  int bx, by, bz;
  if (SWZ == 1) {
    const int gx = gridDim.x, gy = gridDim.y;
    const int f = blockIdx.x + gx * (blockIdx.y + gy * blockIdx.z);
    const int l = (f & 7) * 32 + (f >> 3);          // total == 256
    bx = l % gx;
    const int rr = l / gx;
    by = rr % gy;
    bz = rr / gy;
  } else {  // SWZ==2: grid (2,2,64); 4 tiles of chunk z co-scheduled on one XCD
    const int f = blockIdx.x + 2 * (blockIdx.y + 2 * blockIdx.z);
    const int x = f & 7, s = f >> 3;
    bz = x + 8 * (s >> 2);
    bx = s & 1;
    by = (s >> 1) & 1;
  }
  const long za = bz;
  const __hip_bfloat16* A = Ag + za * sA;
  const __hip_bfloat16* B = Bg + za * sB;

  __shared__ __align__(16) __hip_bfloat16 SB[2][2 * 256 * 64];  // 128KB

  const int tid  = threadIdx.x;
  const int lane = tid & 63;
  const int wid  = tid >> 6;
  const int wr   = wid >> 2;
  const int wc   = wid & 3;
  const int brow = by * 256;
  const int bcol = bx * 256;

  floatx4 acc[8][4];
#pragma unroll
  for (int i = 0; i < 8; i++)
#pragma unroll
    for (int j = 0; j < 4; j++) acc[i][j] = (floatx4){0.f, 0.f, 0.f, 0.f};

  const int srow  = tid >> 3;
  const int skoff = (((tid & 7) ^ (srow & 7))) * 8;

  auto STAGE = [&](int buf, int kt) {
    const int k0 = kt * 64;
#pragma unroll
    for (int r = 0; r < 4; ++r) {
      gload_lds16(A + (size_t)(brow + r * 64 + srow) * 512 + k0 + skoff,
                  (void*)(&SB[buf][0] + r * 4096 + tid * 8));
      gload_lds16(B + (size_t)(bcol + r * 64 + srow) * 512 + k0 + skoff,
                  (void*)(&SB[buf][16384] + r * 4096 + tid * 8));
    }
  };

  const int rs0 = (((lane >> 4)) ^ (lane & 7)) * 8;
  const int rs1 = ((4 + (lane >> 4)) ^ (lane & 7)) * 8;

  STAGE(0, 0);
  STAGE(1, 1);
  asm volatile("s_waitcnt vmcnt(8)" ::: "memory");
  __builtin_amdgcn_s_barrier();
  FENCE();

  for (int kt = 0; kt < 8; ++kt) {
    const int cur = kt & 1;
    const __hip_bfloat16* As = &SB[cur][0];
    const __hip_bfloat16* Bs = &SB[cur][16384];
    __builtin_amdgcn_s_setprio(1);
#pragma unroll
    for (int kk = 0; kk < 2; ++kk) {
      const int rs = kk ? rs1 : rs0;
      short8 a[8], b[4];
#pragma unroll
      for (int i = 0; i < 8; i++)
        a[i] = *(const short8*)(As + (wr * 128 + i * 16 + (lane & 15)) * 64 + rs);
#pragma unroll
      for (int j = 0; j < 4; j++)
        b[j] = *(const short8*)(Bs + (wc * 64 + j * 16 + (lane & 15)) * 64 + rs);
#pragma unroll
      for (int i = 0; i < 8; i++)
#pragma unroll
        for (int j = 0; j < 4; j++)
          acc[i][j] = __builtin_amdgcn_mfma_f32_16x16x32_bf16(a[i], b[j], acc[i][j], 0, 0, 0);
    }
    __builtin_amdgcn_s_setprio(0);

    if (kt < 7) {
      __builtin_amdgcn_s_barrier();
      FENCE();
      if (kt + 2 < 8) {
        STAGE(cur, kt + 2);
        asm volatile("s_waitcnt vmcnt(8)" ::: "memory");
      } else {
        asm volatile("s_waitcnt vmcnt(0)" ::: "memory");
      }
      __builtin_amdgcn_s_barrier();
      FENCE();
    }
  }

  // epilogue: C/D layout col=lane&15, row=(lane>>4)*4+reg
#pragma unroll
  for (int i = 0; i < 8; i++) {
    const int row0 = brow + wr * 128 + i * 16 + (lane >> 4) * 4;
#pragma unroll
    for (int j = 0; j < 4; j++) {
      const int col = bcol + wc * 64 + j * 16 + (lane & 15);
      const float bv = HASBIAS ? bias[col] : 0.f;
#pragma unroll
      for (int r = 0; r < 4; r++) {
        float v = acc[i][j][r] + bv;
        if (GELU_OUT) v = gelu_fast(v);
        if (OUT_F32)
          ((float*)Cg + za * sC)[(size_t)(row0 + r) * 512 + col] = v;
        else
          ((__hip_bfloat16*)Cg + za * sC)[(size_t)(row0 + r) * 512 + col] = __float2bfloat16(v);
      }
    }
  }
}

// ---- named instantiations ----
// A/B: h1 = GELU in epilogue (rcp version); h2 = separate gelu_inplace pass.
__global__ __launch_bounds__(512, 2)
void g256_h1(const __hip_bfloat16* A, const __hip_bfloat16* B, const float* bias, void* C) {
  gemm256_body<true, true, false, 1>(A, B, bias, C, 0, 0, 0);
}
__global__ __launch_bounds__(512, 2)
void g256_w1(const __hip_bfloat16* A, const __hip_bfloat16* B, const float* bias, void* C) {
  gemm256_body<false, true, false, 1>(A, B, bias, C, 0, 0, 0);
}
__global__ __launch_bounds__(512, 2)
void g256_h2(const __hip_bfloat16* A, const __hip_bfloat16* B, const float* bias, void* C) {
  gemm256_body<false, true, false, 1>(A, B, bias, C, 0, 0, 0);
}
__global__ __launch_bounds__(512, 2)
void g256_w2(const __hip_bfloat16* A, const __hip_bfloat16* B, const float* bias, void* C) {
  gemm256_body<false, true, false, 1>(A, B, bias, C, 0, 0, 0);
}
__global__ __launch_bounds__(512, 2)
void g256_p(const __hip_bfloat16* A, const __hip_bfloat16* B, void* C) {
  gemm256_body<false, false, false, 2>(A, B, nullptr, C, 262144, 262144, 262144);
}
__global__ __launch_bounds__(512, 2)
void g256_y(const __hip_bfloat16* A, const __hip_bfloat16* B, void* C) {
  gemm256_body<false, false, true, 1>(A, B, nullptr, C,
                                      4096L * 512, 262144, 4096L * 512);
}

// in-place GELU over bf16 buffer, 8 elems/thread
__global__ __launch_bounds__(256)
void gelu_inplace(__hip_bfloat16* __restrict__ H, long n) {
  long i = ((long)blockIdx.x * 256 + threadIdx.x) * 8;
  if (i >= n) return;
  short8 v = *(const short8*)(H + i);
  short8 o;
#pragma unroll
  for (int j = 0; j < 8; j++) {
    float x = __bfloat162float(((const __hip_bfloat16*)&v)[j]);
    ((__hip_bfloat16*)&o)[j] = __float2bfloat16(gelu_fast(x));
  }
  *(short8*)(H + i) = o;
}

// fp32 -> bf16, 8 elements/thread
__global__ __launch_bounds__(256)
void cvt_f32_bf16(const float* __restrict__ in, __hip_bfloat16* __restrict__ out, long n) {
  long i = ((long)blockIdx.x * 256 + threadIdx.x) * 8;
  if (i >= n) return;
  float4 v0 = *(const float4*)(in + i);
  float4 v1 = *(const float4*)(in + i + 4);
  short8 o;
  __hip_bfloat16* ob = (__hip_bfloat16*)&o;
  ob[0] = __float2bfloat16(v0.x); ob[1] = __float2bfloat16(v0.y);
  ob[2] = __float2bfloat16(v0.z); ob[3] = __float2bfloat16(v0.w);
  ob[4] = __float2bfloat16(v1.x); ob[5] = __float2bfloat16(v1.y);
  ob[6] = __float2bfloat16(v1.z); ob[7] = __float2bfloat16(v1.w);
  *(short8*)(out + i) = o;
}

// X fp32 [B][4096][512] -> Xb bf16 + XTc bf16 [B*8][512 d][512 n]  (proven R5-R11)
__global__ __launch_bounds__(256)
void cvt_x_xt(const float* __restrict__ X,
              __hip_bfloat16* __restrict__ Xb,
              __hip_bfloat16* __restrict__ XT)
{
  __shared__ __hip_bfloat16 t[64][66];
  const int b  = blockIdx.z;
  const int n0 = blockIdx.y * 64;
  const int d0 = blockIdx.x * 64;
  const float* I = X + (size_t)b * 4096 * 512;
  __hip_bfloat16* XB = Xb + (size_t)b * 4096 * 512;
  __hip_bfloat16* XO = XT + ((size_t)b * 8 + (n0 >> 9)) * 512 * 512;
  const int nl0 = n0 & 511;
  const int tid = threadIdx.x;
#pragma unroll
  for (int it = 0; it < 4; ++it) {
    const int idx = it * 256 + tid;
    const int r   = idx >> 4;
    const int c4  = (idx & 15) * 4;
    float4 v = *(const float4*)&I[(size_t)(n0 + r) * 512 + d0 + c4];
    short4v o;
    __hip_bfloat16* ob = (__hip_bfloat16*)&o;
    ob[0] = __float2bfloat16(v.x); ob[1] = __float2bfloat16(v.y);
    ob[2] = __float2bfloat16(v.z); ob[3] = __float2bfloat16(v.w);
    t[r][c4]     = ob[0]; t[r][c4 + 1] = ob[1];
    t[r][c4 + 2] = ob[2]; t[r][c4 + 3] = ob[3];
    *(short4v*)&XB[(size_t)(n0 + r) * 512 + d0 + c4] = o;
  }
  __syncthreads();
#pragma unroll
  for (int it = 0; it < 4; ++it) {
    const int idx = it * 256 + tid;
    const int dr  = idx >> 4;
    const int n4  = (idx & 15) * 4;
    short4v o;
    __hip_bfloat16* ob = (__hip_bfloat16*)&o;
#pragma unroll
    for (int j = 0; j < 4; j++) ob[j] = t[n4 + j][dr];
    *(short4v*)&XO[(size_t)(d0 + dr) * 512 + nl0 + n4] = o;
  }
}

// W1n [32768 n][512 p] bf16 -> W1Tc [64 chunks][512 p][512 n-local]
__global__ __launch_bounds__(256)
void transpose_w1(const __hip_bfloat16* __restrict__ in,
                  __hip_bfloat16* __restrict__ out)
{
  __shared__ __hip_bfloat16 t[64][66];
  const int b  = blockIdx.z;
  const int n0 = blockIdx.y * 64;      // n within batch (0..4032)
  const int p0 = blockIdx.x * 64;
  const __hip_bfloat16* I = in + (size_t)b * 4096 * 512;
  __hip_bfloat16* O = out + ((size_t)b * 8 + (n0 >> 9)) * 512 * 512;
  const int nl0 = n0 & 511;
  const int tid = threadIdx.x;
#pragma unroll
  for (int it = 0; it < 2; ++it) {
    const int idx = it * 256 + tid;    // 0..511
    const int r   = idx >> 3;          // n-local 0..63
    const int c8  = (idx & 7) * 8;     // p-local 0..56
    short8 v = *(const short8*)&I[(size_t)(n0 + r) * 512 + p0 + c8];
#pragma unroll
    for (int j = 0; j < 8; j++) t[r][c8 + j] = ((const __hip_bfloat16*)&v)[j];
  }
  __syncthreads();
#pragma unroll
  for (int it = 0; it < 2; ++it) {
    const int idx = it * 256 + tid;
    const int dr  = idx >> 3;          // p-local 0..63
    const int n8  = (idx & 7) * 8;     // n-local 0..56
    short8 o;
#pragma unroll
    for (int j = 0; j < 8; j++) ((__hip_bfloat16*)&o)[j] = t[n8 + j][dr];
    *(short8*)&O[(size_t)(p0 + dr) * 512 + nl0 + n8] = o;
  }
}

// AT[b][i] = bf16(GELU(sum_kc part[(b*8+kc)][i]))
__global__ __launch_bounds__(256)
void reduce_gelu_bf16(const __hip_bfloat16* __restrict__ part,
                      __hip_bfloat16* __restrict__ AT) {
  const long o = ((long)blockIdx.x * 256 + threadIdx.x) * 8;
  const long b = o >> 18;
  const long i = o & 262143;
  float s[8] = {0.f, 0.f, 0.f, 0.f, 0.f, 0.f, 0.f, 0.f};
#pragma unroll
  for (int kc = 0; kc < 8; kc++) {
    short8 v = *(const short8*)(part + (((b << 3) + kc) << 18) + i);
#pragma unroll
    for (int j = 0; j < 8; j++) s[j] += __bfloat162float(((const __hip_bfloat16*)&v)[j]);
  }
  short8 o8;
#pragma unroll
  for (int j = 0; j < 8; j++)
    ((__hip_bfloat16*)&o8)[j] = __float2bfloat16(gelu_fast(s[j]));
  *(short8*)(AT + o) = o8;
}

extern "C" void kernel_launch(void* const* d_in, const int* in_sizes, int n_in,
                              void* d_out, int out_size, void* d_ws, size_t ws_size,
                              hipStream_t stream) {
  const float* X   = (const float*)d_in[0];
  const float* W1a = (const float*)d_in[1];
  const float* b1a = (const float*)d_in[2];
  const float* W1b = (const float*)d_in[3];
  const float* b1b = (const float*)d_in[4];
  const float* W2a = (const float*)d_in[5];
  const float* b2a = (const float*)d_in[6];
  const float* W2b = (const float*)d_in[7];
  const float* b2b = (const float*)d_in[8];
  float* Y = (float*)d_out;

  char* ws = (char*)d_ws;
  const size_t SZ = 33554432;  // 32768*512*2 B
  // region 0: Xb -> (after h2) W1Tc -> (after P) W2m
  // region 1: H (H1, then H2)
  // region 2: W1n -> (after transpose) part
  // region 3: XTc
  __hip_bfloat16* R0 = (__hip_bfloat16*)(ws);
  __hip_bfloat16* R1 = (__hip_bfloat16*)(ws + SZ);
  __hip_bfloat16* R2 = (__hip_bfloat16*)(ws + 2 * SZ);
  __hip_bfloat16* R3 = (__hip_bfloat16*)(ws + 3 * SZ);
  __hip_bfloat16* AT = (__hip_bfloat16*)(ws + 4 * SZ);           // 4MB
  __hip_bfloat16* Wb = (__hip_bfloat16*)(ws + 4 * SZ + 4194304); // 2MB
  __hip_bfloat16* W1ab = Wb;
  __hip_bfloat16* W1bb = Wb + 262144;
  __hip_bfloat16* W2ab = Wb + 2 * 262144;
  __hip_bfloat16* W2bb = Wb + 3 * 262144;

  dim3 blk(256), blk512(512);

  // 0) conversions; X also emits chunked XTc
  cvt_f32_bf16<<<128,  blk, 0, stream>>>(W1a, W1ab, 262144L);
  cvt_f32_bf16<<<128,  blk, 0, stream>>>(W1b, W1bb, 262144L);
  cvt_f32_bf16<<<128,  blk, 0, stream>>>(W2a, W2ab, 262144L);
  cvt_f32_bf16<<<128,  blk, 0, stream>>>(W2b, W2bb, 262144L);
  __hip_bfloat16* Xb  = R0;
  __hip_bfloat16* XTc = R3;
  cvt_x_xt<<<dim3(8, 64, 8), blk, 0, stream>>>(X, Xb, XTc);

  // 1) H1 = GELU(Xb @ W1a^T + b1a)   [epilogue GELU — A/B arm A]
  __hip_bfloat16* H = R1;
  g256_h1<<<dim3(2, 128, 1), blk512, 0, stream>>>(Xb, W1ab, b1a, H);
  // 2) W1n = H1 @ W1b^T + b1b (natural layout)
  __hip_bfloat16* W1n = R2;
  g256_w1<<<dim3(2, 128, 1), blk512, 0, stream>>>(H, W1bb, b1b, W1n);
  // 3) H2 = Xb @ W2a^T + b2a ; GELU separate  [A/B arm B]  (Xb dead after)
  g256_h2<<<dim3(2, 128, 1), blk512, 0, stream>>>(Xb, W2ab, b2a, H);
  gelu_inplace<<<8192, blk, 0, stream>>>(H, 16777216L);
  // 4) W1Tc = chunk-transpose(W1n) -> region 0 (Xb dead); W1n dead after
  __hip_bfloat16* W1Tc = R0;
  transpose_w1<<<dim3(8, 64, 8), blk, 0, stream>>>(W1n, W1Tc);
  // 5) P partials: part[z] = XTc[z] @ W1Tc[z]^T -> region 2 (W1n dead)
  __hip_bfloat16* part = R2;
  g256_p<<<dim3(2, 2, 64), blk512, 0, stream>>>(XTc, W1Tc, part);
  // 6) AT = GELU(sum_kc part)
  reduce_gelu_bf16<<<1024, blk, 0, stream>>>(part, AT);
  // 7) W2m = H2 @ W2b^T + b2b -> region 0 (W1Tc dead after P)
  __hip_bfloat16* W2m = R0;
  g256_w2<<<dim3(2, 128, 1), blk512, 0, stream>>>(H, W2bb, b2b, W2m);
  // 8) Y = W2m @ AT^T per batch -> fp32
  g256_y<<<dim3(2, 16, 8), blk512, 0, stream>>>(W2m, AT, Y);
}

// Round 16
// 236.760 us; speedup vs baseline: 1.0635x; 1.0635x over previous
//
#include <hip/hip_runtime.h>
#include <hip/hip_bf16.h>

typedef __attribute__((ext_vector_type(8))) short short8;
typedef __attribute__((ext_vector_type(4))) short short4v;
typedef __attribute__((ext_vector_type(4))) float floatx4;

__device__ __forceinline__ void gload_lds16(const void* g, void* l) {
  __builtin_amdgcn_global_load_lds(
      (const __attribute__((address_space(1))) void*)g,
      (__attribute__((address_space(3))) void*)l, 16, 0, 0);
}

// tanh-approx GELU via sigmoid; branch-free (v_exp + v_rcp)
__device__ __forceinline__ float gelu_fast(float x) {
  float z = 1.5957691216f * (x + 0.044715f * x * x * x);
  float e = __expf(-z);
  return x * __builtin_amdgcn_rcpf(1.0f + e);
}

#define FENCE() asm volatile("" ::: "memory")

// ================= 256x256x(K=512) counted-vmcnt NT GEMM =================
// C[M,512] = epi(A[M,512] @ B[512,512]^T + bias); 512 thr (8 waves, 2x4),
// per-wave out 128x64, BK=64, dbuf LDS 128KB.
// T2 swizzle via pre-swizzled global source; T4 counted-vmcnt pipeline.
// NOTE: GELU-in-epilogue is BANNED — measured +32us pathology (R14 A/B).
// SWZ=1: chunked XCD (grid total must be 256). SWZ=2: P-grid (2,2,64).
template<bool HASBIAS, bool OUT_F32, int SWZ>
__device__ __forceinline__
void gemm256_body(const __hip_bfloat16* __restrict__ Ag,
                  const __hip_bfloat16* __restrict__ Bg,
                  const float* __restrict__ bias,
                  void* __restrict__ Cg,
                  long sA, long sB, long sC)
{
  int bx, by, bz;
  if (SWZ == 1) {
    const int gx = gridDim.x, gy = gridDim.y;
    const int f = blockIdx.x + gx * (blockIdx.y + gy * blockIdx.z);
    const int l = (f & 7) * 32 + (f >> 3);          // total == 256
    bx = l % gx;
    const int rr = l / gx;
    by = rr % gy;
    bz = rr / gy;
  } else {  // SWZ==2: grid (2,2,64); 4 tiles of chunk z co-scheduled on one XCD
    const int f = blockIdx.x + 2 * (blockIdx.y + 2 * blockIdx.z);
    const int x = f & 7, s = f >> 3;
    bz = x + 8 * (s >> 2);
    bx = s & 1;
    by = (s >> 1) & 1;
  }
  const long za = bz;
  const __hip_bfloat16* A = Ag + za * sA;
  const __hip_bfloat16* B = Bg + za * sB;

  __shared__ __align__(16) __hip_bfloat16 SB[2][2 * 256 * 64];  // 128KB

  const int tid  = threadIdx.x;
  const int lane = tid & 63;
  const int wid  = tid >> 6;
  const int wr   = wid >> 2;
  const int wc   = wid & 3;
  const int brow = by * 256;
  const int bcol = bx * 256;

  floatx4 acc[8][4];
#pragma unroll
  for (int i = 0; i < 8; i++)
#pragma unroll
    for (int j = 0; j < 4; j++) acc[i][j] = (floatx4){0.f, 0.f, 0.f, 0.f};

  const int srow  = tid >> 3;
  const int skoff = (((tid & 7) ^ (srow & 7))) * 8;

  auto STAGE = [&](int buf, int kt) {
    const int k0 = kt * 64;
#pragma unroll
    for (int r = 0; r < 4; ++r) {
      gload_lds16(A + (size_t)(brow + r * 64 + srow) * 512 + k0 + skoff,
                  (void*)(&SB[buf][0] + r * 4096 + tid * 8));
      gload_lds16(B + (size_t)(bcol + r * 64 + srow) * 512 + k0 + skoff,
                  (void*)(&SB[buf][16384] + r * 4096 + tid * 8));
    }
  };

  const int rs0 = (((lane >> 4)) ^ (lane & 7)) * 8;
  const int rs1 = ((4 + (lane >> 4)) ^ (lane & 7)) * 8;

  STAGE(0, 0);
  STAGE(1, 1);
  asm volatile("s_waitcnt vmcnt(8)" ::: "memory");
  __builtin_amdgcn_s_barrier();
  FENCE();

  for (int kt = 0; kt < 8; ++kt) {
    const int cur = kt & 1;
    const __hip_bfloat16* As = &SB[cur][0];
    const __hip_bfloat16* Bs = &SB[cur][16384];
    __builtin_amdgcn_s_setprio(1);
#pragma unroll
    for (int kk = 0; kk < 2; ++kk) {
      const int rs = kk ? rs1 : rs0;
      short8 a[8], b[4];
#pragma unroll
      for (int i = 0; i < 8; i++)
        a[i] = *(const short8*)(As + (wr * 128 + i * 16 + (lane & 15)) * 64 + rs);
#pragma unroll
      for (int j = 0; j < 4; j++)
        b[j] = *(const short8*)(Bs + (wc * 64 + j * 16 + (lane & 15)) * 64 + rs);
#pragma unroll
      for (int i = 0; i < 8; i++)
#pragma unroll
        for (int j = 0; j < 4; j++)
          acc[i][j] = __builtin_amdgcn_mfma_f32_16x16x32_bf16(a[i], b[j], acc[i][j], 0, 0, 0);
    }
    __builtin_amdgcn_s_setprio(0);

    if (kt < 7) {
      __builtin_amdgcn_s_barrier();
      FENCE();
      if (kt + 2 < 8) {
        STAGE(cur, kt + 2);
        asm volatile("s_waitcnt vmcnt(8)" ::: "memory");
      } else {
        asm volatile("s_waitcnt vmcnt(0)" ::: "memory");
      }
      __builtin_amdgcn_s_barrier();
      FENCE();
    }
  }

  // epilogue: C/D layout col=lane&15, row=(lane>>4)*4+reg
#pragma unroll
  for (int i = 0; i < 8; i++) {
    const int row0 = brow + wr * 128 + i * 16 + (lane >> 4) * 4;
#pragma unroll
    for (int j = 0; j < 4; j++) {
      const int col = bcol + wc * 64 + j * 16 + (lane & 15);
      const float bv = HASBIAS ? bias[col] : 0.f;
#pragma unroll
      for (int r = 0; r < 4; r++) {
        float v = acc[i][j][r] + bv;
        if (OUT_F32)
          ((float*)Cg + za * sC)[(size_t)(row0 + r) * 512 + col] = v;
        else
          ((__hip_bfloat16*)Cg + za * sC)[(size_t)(row0 + r) * 512 + col] = __float2bfloat16(v);
      }
    }
  }
}

// ---- named instantiations (all GELU-free) ----
__global__ __launch_bounds__(512, 2)
void g256_h1(const __hip_bfloat16* A, const __hip_bfloat16* B, const float* bias, void* C) {
  gemm256_body<true, false, 1>(A, B, bias, C, 0, 0, 0);
}
__global__ __launch_bounds__(512, 2)
void g256_w1(const __hip_bfloat16* A, const __hip_bfloat16* B, const float* bias, void* C) {
  gemm256_body<true, false, 1>(A, B, bias, C, 0, 0, 0);
}
__global__ __launch_bounds__(512, 2)
void g256_h2(const __hip_bfloat16* A, const __hip_bfloat16* B, const float* bias, void* C) {
  gemm256_body<true, false, 1>(A, B, bias, C, 0, 0, 0);
}
__global__ __launch_bounds__(512, 2)
void g256_w2(const __hip_bfloat16* A, const __hip_bfloat16* B, const float* bias, void* C) {
  gemm256_body<true, false, 1>(A, B, bias, C, 0, 0, 0);
}
__global__ __launch_bounds__(512, 2)
void g256_p(const __hip_bfloat16* A, const __hip_bfloat16* B, void* C) {
  gemm256_body<false, false, 2>(A, B, nullptr, C, 262144, 262144, 262144);
}
__global__ __launch_bounds__(512, 2)
void g256_y(const __hip_bfloat16* A, const __hip_bfloat16* B, void* C) {
  gemm256_body<false, true, 1>(A, B, nullptr, C,
                               4096L * 512, 262144, 4096L * 512);
}

// in-place GELU over bf16 buffer, 8 elems/thread
__global__ __launch_bounds__(256)
void gelu_inplace(__hip_bfloat16* __restrict__ H, long n) {
  long i = ((long)blockIdx.x * 256 + threadIdx.x) * 8;
  if (i >= n) return;
  short8 v = *(const short8*)(H + i);
  short8 o;
#pragma unroll
  for (int j = 0; j < 8; j++) {
    float x = __bfloat162float(((const __hip_bfloat16*)&v)[j]);
    ((__hip_bfloat16*)&o)[j] = __float2bfloat16(gelu_fast(x));
  }
  *(short8*)(H + i) = o;
}

// fused fp32->bf16 for the four 512x512 weights (one launch)
__global__ __launch_bounds__(256)
void cvt_w4(const float* __restrict__ w0, const float* __restrict__ w1,
            const float* __restrict__ w2, const float* __restrict__ w3,
            __hip_bfloat16* __restrict__ o0, __hip_bfloat16* __restrict__ o1,
            __hip_bfloat16* __restrict__ o2, __hip_bfloat16* __restrict__ o3) {
  const int sel = blockIdx.x >> 7;           // 128 blocks per weight
  const float* in = sel == 0 ? w0 : sel == 1 ? w1 : sel == 2 ? w2 : w3;
  __hip_bfloat16* out = sel == 0 ? o0 : sel == 1 ? o1 : sel == 2 ? o2 : o3;
  const long i = (((long)(blockIdx.x & 127)) * 256 + threadIdx.x) * 8;
  float4 v0 = *(const float4*)(in + i);
  float4 v1 = *(const float4*)(in + i + 4);
  short8 o;
  __hip_bfloat16* ob = (__hip_bfloat16*)&o;
  ob[0] = __float2bfloat16(v0.x); ob[1] = __float2bfloat16(v0.y);
  ob[2] = __float2bfloat16(v0.z); ob[3] = __float2bfloat16(v0.w);
  ob[4] = __float2bfloat16(v1.x); ob[5] = __float2bfloat16(v1.y);
  ob[6] = __float2bfloat16(v1.z); ob[7] = __float2bfloat16(v1.w);
  *(short8*)(out + i) = o;
}

// X fp32 [B][4096][512] -> Xb bf16 + XTc bf16 [B*8][512 d][512 n]
__global__ __launch_bounds__(256)
void cvt_x_xt(const float* __restrict__ X,
              __hip_bfloat16* __restrict__ Xb,
              __hip_bfloat16* __restrict__ XT)
{
  __shared__ __hip_bfloat16 t[64][66];
  const int b  = blockIdx.z;
  const int n0 = blockIdx.y * 64;
  const int d0 = blockIdx.x * 64;
  const float* I = X + (size_t)b * 4096 * 512;
  __hip_bfloat16* XB = Xb + (size_t)b * 4096 * 512;
  __hip_bfloat16* XO = XT + ((size_t)b * 8 + (n0 >> 9)) * 512 * 512;
  const int nl0 = n0 & 511;
  const int tid = threadIdx.x;
#pragma unroll
  for (int it = 0; it < 4; ++it) {
    const int idx = it * 256 + tid;
    const int r   = idx >> 4;
    const int c4  = (idx & 15) * 4;
    float4 v = *(const float4*)&I[(size_t)(n0 + r) * 512 + d0 + c4];
    short4v o;
    __hip_bfloat16* ob = (__hip_bfloat16*)&o;
    ob[0] = __float2bfloat16(v.x); ob[1] = __float2bfloat16(v.y);
    ob[2] = __float2bfloat16(v.z); ob[3] = __float2bfloat16(v.w);
    t[r][c4]     = ob[0]; t[r][c4 + 1] = ob[1];
    t[r][c4 + 2] = ob[2]; t[r][c4 + 3] = ob[3];
    *(short4v*)&XB[(size_t)(n0 + r) * 512 + d0 + c4] = o;
  }
  __syncthreads();
#pragma unroll
  for (int it = 0; it < 4; ++it) {
    const int idx = it * 256 + tid;
    const int dr  = idx >> 4;
    const int n4  = (idx & 15) * 4;
    short4v o;
    __hip_bfloat16* ob = (__hip_bfloat16*)&o;
#pragma unroll
    for (int j = 0; j < 4; j++) ob[j] = t[n4 + j][dr];
    *(short4v*)&XO[(size_t)(d0 + dr) * 512 + nl0 + n4] = o;
  }
}

// W1n [32768 n][512 p] bf16 -> W1Tc [64 chunks][512 p][512 n-local]
__global__ __launch_bounds__(256)
void transpose_w1(const __hip_bfloat16* __restrict__ in,
                  __hip_bfloat16* __restrict__ out)
{
  __shared__ __hip_bfloat16 t[64][66];
  const int b  = blockIdx.z;
  const int n0 = blockIdx.y * 64;
  const int p0 = blockIdx.x * 64;
  const __hip_bfloat16* I = in + (size_t)b * 4096 * 512;
  __hip_bfloat16* O = out + ((size_t)b * 8 + (n0 >> 9)) * 512 * 512;
  const int nl0 = n0 & 511;
  const int tid = threadIdx.x;
#pragma unroll
  for (int it = 0; it < 2; ++it) {
    const int idx = it * 256 + tid;
    const int r   = idx >> 3;
    const int c8  = (idx & 7) * 8;
    short8 v = *(const short8*)&I[(size_t)(n0 + r) * 512 + p0 + c8];
#pragma unroll
    for (int j = 0; j < 8; j++) t[r][c8 + j] = ((const __hip_bfloat16*)&v)[j];
  }
  __syncthreads();
#pragma unroll
  for (int it = 0; it < 2; ++it) {
    const int idx = it * 256 + tid;
    const int dr  = idx >> 3;
    const int n8  = (idx & 7) * 8;
    short8 o;
#pragma unroll
    for (int j = 0; j < 8; j++) ((__hip_bfloat16*)&o)[j] = t[n8 + j][dr];
    *(short8*)&O[(size_t)(p0 + dr) * 512 + nl0 + n8] = o;
  }
}

// AT[b][i] = bf16(GELU(sum_kc part[(b*8+kc)][i]))
__global__ __launch_bounds__(256)
void reduce_gelu_bf16(const __hip_bfloat16* __restrict__ part,
                      __hip_bfloat16* __restrict__ AT) {
  const long o = ((long)blockIdx.x * 256 + threadIdx.x) * 8;
  const long b = o >> 18;
  const long i = o & 262143;
  float s[8] = {0.f, 0.f, 0.f, 0.f, 0.f, 0.f, 0.f, 0.f};
#pragma unroll
  for (int kc = 0; kc < 8; kc++) {
    short8 v = *(const short8*)(part + (((b << 3) + kc) << 18) + i);
#pragma unroll
    for (int j = 0; j < 8; j++) s[j] += __bfloat162float(((const __hip_bfloat16*)&v)[j]);
  }
  short8 o8;
#pragma unroll
  for (int j = 0; j < 8; j++)
    ((__hip_bfloat16*)&o8)[j] = __float2bfloat16(gelu_fast(s[j]));
  *(short8*)(AT + o) = o8;
}

extern "C" void kernel_launch(void* const* d_in, const int* in_sizes, int n_in,
                              void* d_out, int out_size, void* d_ws, size_t ws_size,
                              hipStream_t stream) {
  const float* X   = (const float*)d_in[0];
  const float* W1a = (const float*)d_in[1];
  const float* b1a = (const float*)d_in[2];
  const float* W1b = (const float*)d_in[3];
  const float* b1b = (const float*)d_in[4];
  const float* W2a = (const float*)d_in[5];
  const float* b2a = (const float*)d_in[6];
  const float* W2b = (const float*)d_in[7];
  const float* b2b = (const float*)d_in[8];
  float* Y = (float*)d_out;

  char* ws = (char*)d_ws;
  const size_t SZ = 33554432;  // 32768*512*2 B
  // region 0: Xb -> (after h2) W1Tc -> (after P) W2m
  // region 1: H (H1, then H2)
  // region 2: W1n -> (after transpose) part
  // region 3: XTc
  __hip_bfloat16* R0 = (__hip_bfloat16*)(ws);
  __hip_bfloat16* R1 = (__hip_bfloat16*)(ws + SZ);
  __hip_bfloat16* R2 = (__hip_bfloat16*)(ws + 2 * SZ);
  __hip_bfloat16* R3 = (__hip_bfloat16*)(ws + 3 * SZ);
  __hip_bfloat16* AT = (__hip_bfloat16*)(ws + 4 * SZ);           // 4MB
  __hip_bfloat16* Wb = (__hip_bfloat16*)(ws + 4 * SZ + 4194304); // 2MB
  __hip_bfloat16* W1ab = Wb;
  __hip_bfloat16* W1bb = Wb + 262144;
  __hip_bfloat16* W2ab = Wb + 2 * 262144;
  __hip_bfloat16* W2bb = Wb + 3 * 262144;

  dim3 blk(256), blk512(512);

  // 0) conversions; X also emits chunked XTc
  cvt_w4<<<512, blk, 0, stream>>>(W1a, W1b, W2a, W2b, W1ab, W1bb, W2ab, W2bb);
  __hip_bfloat16* Xb  = R0;
  __hip_bfloat16* XTc = R3;
  cvt_x_xt<<<dim3(8, 64, 8), blk, 0, stream>>>(X, Xb, XTc);

  // 1) H1 = Xb @ W1a^T + b1a ; GELU separate
  __hip_bfloat16* H = R1;
  g256_h1<<<dim3(2, 128, 1), blk512, 0, stream>>>(Xb, W1ab, b1a, H);
  gelu_inplace<<<8192, blk, 0, stream>>>(H, 16777216L);
  // 2) W1n = H1 @ W1b^T + b1b (natural layout)
  __hip_bfloat16* W1n = R2;
  g256_w1<<<dim3(2, 128, 1), blk512, 0, stream>>>(H, W1bb, b1b, W1n);
  // 3) H2 = Xb @ W2a^T + b2a ; GELU separate  (Xb dead after)
  g256_h2<<<dim3(2, 128, 1), blk512, 0, stream>>>(Xb, W2ab, b2a, H);
  gelu_inplace<<<8192, blk, 0, stream>>>(H, 16777216L);
  // 4) W1Tc = chunk-transpose(W1n) -> region 0 (Xb dead); W1n dead after
  __hip_bfloat16* W1Tc = R0;
  transpose_w1<<<dim3(8, 64, 8), blk, 0, stream>>>(W1n, W1Tc);
  // 5) P partials: part[z] = XTc[z] @ W1Tc[z]^T -> region 2 (W1n dead)
  __hip_bfloat16* part = R2;
  g256_p<<<dim3(2, 2, 64), blk512, 0, stream>>>(XTc, W1Tc, part);
  // 6) AT = GELU(sum_kc part)
  reduce_gelu_bf16<<<1024, blk, 0, stream>>>(part, AT);
  // 7) W2m = H2 @ W2b^T + b2b -> region 0 (W1Tc dead after P)
  __hip_bfloat16* W2m = R0;
  g256_w2<<<dim3(2, 128, 1), blk512, 0, stream>>>(H, W2bb, b2b, W2m);
  // 8) Y = W2m @ AT^T per batch -> fp32
  g256_y<<<dim3(2, 16, 8), blk512, 0, stream>>>(W2m, AT, Y);
}

// Round 17
// 213.594 us; speedup vs baseline: 1.1788x; 1.1085x over previous
//
#include <hip/hip_runtime.h>
#include <hip/hip_bf16.h>

typedef __attribute__((ext_vector_type(8))) short short8;
typedef __attribute__((ext_vector_type(4))) short short4v;
typedef __attribute__((ext_vector_type(4))) float floatx4;

__device__ __forceinline__ void gload_lds16(const void* g, void* l) {
  __builtin_amdgcn_global_load_lds(
      (const __attribute__((address_space(1))) void*)g,
      (__attribute__((address_space(3))) void*)l, 16, 0, 0);
}

// tanh-approx GELU via sigmoid; branch-free (v_exp + v_rcp)
__device__ __forceinline__ float gelu_fast(float x) {
  float z = 1.5957691216f * (x + 0.044715f * x * x * x);
  float e = __expf(-z);
  return x * __builtin_amdgcn_rcpf(1.0f + e);
}

#define FENCE() asm volatile("" ::: "memory")

// ================= 256x256x(K=512) counted-vmcnt NT GEMM =================
// (proven R11-R16) NOTE: GELU-in-epilogue BANNED (R14 A/B: +32us pathology).
template<bool HASBIAS, bool OUT_F32, int SWZ>
__device__ __forceinline__
void gemm256_body(const __hip_bfloat16* __restrict__ Ag,
                  const __hip_bfloat16* __restrict__ Bg,
                  const float* __restrict__ bias,
                  void* __restrict__ Cg,
                  long sA, long sB, long sC)
{
  int bx, by, bz;
  {
    const int gx = gridDim.x, gy = gridDim.y;
    const int f = blockIdx.x + gx * (blockIdx.y + gy * blockIdx.z);
    const int l = (f & 7) * 32 + (f >> 3);          // total == 256
    bx = l % gx;
    const int rr = l / gx;
    by = rr % gy;
    bz = rr / gy;
  }
  const long za = bz;
  const __hip_bfloat16* A = Ag + za * sA;
  const __hip_bfloat16* B = Bg + za * sB;

  __shared__ __align__(16) __hip_bfloat16 SB[2][2 * 256 * 64];  // 128KB

  const int tid  = threadIdx.x;
  const int lane = tid & 63;
  const int wid  = tid >> 6;
  const int wr   = wid >> 2;
  const int wc   = wid & 3;
  const int brow = by * 256;
  const int bcol = bx * 256;

  floatx4 acc[8][4];
#pragma unroll
  for (int i = 0; i < 8; i++)
#pragma unroll
    for (int j = 0; j < 4; j++) acc[i][j] = (floatx4){0.f, 0.f, 0.f, 0.f};

  const int srow  = tid >> 3;
  const int skoff = (((tid & 7) ^ (srow & 7))) * 8;

  auto STAGE = [&](int buf, int kt) {
    const int k0 = kt * 64;
#pragma unroll
    for (int r = 0; r < 4; ++r) {
      gload_lds16(A + (size_t)(brow + r * 64 + srow) * 512 + k0 + skoff,
                  (void*)(&SB[buf][0] + r * 4096 + tid * 8));
      gload_lds16(B + (size_t)(bcol + r * 64 + srow) * 512 + k0 + skoff,
                  (void*)(&SB[buf][16384] + r * 4096 + tid * 8));
    }
  };

  const int rs0 = (((lane >> 4)) ^ (lane & 7)) * 8;
  const int rs1 = ((4 + (lane >> 4)) ^ (lane & 7)) * 8;

  STAGE(0, 0);
  STAGE(1, 1);
  asm volatile("s_waitcnt vmcnt(8)" ::: "memory");
  __builtin_amdgcn_s_barrier();
  FENCE();

  for (int kt = 0; kt < 8; ++kt) {
    const int cur = kt & 1;
    const __hip_bfloat16* As = &SB[cur][0];
    const __hip_bfloat16* Bs = &SB[cur][16384];
    __builtin_amdgcn_s_setprio(1);
#pragma unroll
    for (int kk = 0; kk < 2; ++kk) {
      const int rs = kk ? rs1 : rs0;
      short8 a[8], b[4];
#pragma unroll
      for (int i = 0; i < 8; i++)
        a[i] = *(const short8*)(As + (wr * 128 + i * 16 + (lane & 15)) * 64 + rs);
#pragma unroll
      for (int j = 0; j < 4; j++)
        b[j] = *(const short8*)(Bs + (wc * 64 + j * 16 + (lane & 15)) * 64 + rs);
#pragma unroll
      for (int i = 0; i < 8; i++)
#pragma unroll
        for (int j = 0; j < 4; j++)
          acc[i][j] = __builtin_amdgcn_mfma_f32_16x16x32_bf16(a[i], b[j], acc[i][j], 0, 0, 0);
    }
    __builtin_amdgcn_s_setprio(0);

    if (kt < 7) {
      __builtin_amdgcn_s_barrier();
      FENCE();
      if (kt + 2 < 8) {
        STAGE(cur, kt + 2);
        asm volatile("s_waitcnt vmcnt(8)" ::: "memory");
      } else {
        asm volatile("s_waitcnt vmcnt(0)" ::: "memory");
      }
      __builtin_amdgcn_s_barrier();
      FENCE();
    }
  }

#pragma unroll
  for (int i = 0; i < 8; i++) {
    const int row0 = brow + wr * 128 + i * 16 + (lane >> 4) * 4;
#pragma unroll
    for (int j = 0; j < 4; j++) {
      const int col = bcol + wc * 64 + j * 16 + (lane & 15);
      const float bv = HASBIAS ? bias[col] : 0.f;
#pragma unroll
      for (int r = 0; r < 4; r++) {
        float v = acc[i][j][r] + bv;
        if (OUT_F32)
          ((float*)Cg + za * sC)[(size_t)(row0 + r) * 512 + col] = v;
        else
          ((__hip_bfloat16*)Cg + za * sC)[(size_t)(row0 + r) * 512 + col] = __float2bfloat16(v);
      }
    }
  }
}

// ================= 128x128x(K=512) counted-vmcnt NT GEMM =================
// 256 thr (4 waves 2x2), per-wave out 64x64, BK=64, dbuf LDS 64KB -> 2 blk/CU.
// Same T2 swizzle + T4 pipeline as gemm256. For y (store overlap) and P.
// SWZ=1: per-XCD batch grouping (grid total must be 1024, gz = batches).
// SWZ=2: P-grid (4,4,64): 16 tiles per chunk z grouped per XCD.
template<bool OUT_F32, int SWZ>
__device__ __forceinline__
void gemm128_body(const __hip_bfloat16* __restrict__ Ag,
                  const __hip_bfloat16* __restrict__ Bg,
                  void* __restrict__ Cg,
                  long sA, long sB, long sC)
{
  int bx, by, bz;
  if (SWZ == 1) {
    const int gx = gridDim.x, gy = gridDim.y;
    const int f = blockIdx.x + gx * (blockIdx.y + gy * blockIdx.z);
    const int total = gx * gy * gridDim.z;          // 1024
    const int l = (f & 7) * (total >> 3) + (f >> 3);
    bx = l % gx;
    const int rr = l / gx;
    by = rr % gy;
    bz = rr / gy;
  } else {  // grid (4,4,64)
    const int f = blockIdx.x + 4 * (blockIdx.y + 4 * blockIdx.z);
    const int xcd = f & 7, s = f >> 3;              // s: 0..127
    bz = xcd + 8 * (s >> 4);
    const int t = s & 15;
    by = t >> 2;
    bx = t & 3;
  }
  const long za = bz;
  const __hip_bfloat16* A = Ag + za * sA;
  const __hip_bfloat16* B = Bg + za * sB;

  __shared__ __align__(16) __hip_bfloat16 SB[2][2 * 128 * 64];  // 64KB

  const int tid  = threadIdx.x;
  const int lane = tid & 63;
  const int wid  = tid >> 6;   // 0..3
  const int wr   = wid >> 1;   // 0..1
  const int wc   = wid & 1;    // 0..1
  const int brow = by * 128;
  const int bcol = bx * 128;

  floatx4 acc[4][4];
#pragma unroll
  for (int i = 0; i < 4; i++)
#pragma unroll
    for (int j = 0; j < 4; j++) acc[i][j] = (floatx4){0.f, 0.f, 0.f, 0.f};

  const int srow  = tid >> 3;                       // 0..31
  const int skoff = (((tid & 7) ^ (srow & 7))) * 8;

  auto STAGE = [&](int buf, int kt) {
    const int k0 = kt * 64;
#pragma unroll
    for (int r = 0; r < 4; ++r) {
      gload_lds16(A + (size_t)(brow + r * 32 + srow) * 512 + k0 + skoff,
                  (void*)(&SB[buf][0] + r * 2048 + tid * 8));
      gload_lds16(B + (size_t)(bcol + r * 32 + srow) * 512 + k0 + skoff,
                  (void*)(&SB[buf][8192] + r * 2048 + tid * 8));
    }
  };

  const int rs0 = (((lane >> 4)) ^ (lane & 7)) * 8;
  const int rs1 = ((4 + (lane >> 4)) ^ (lane & 7)) * 8;

  STAGE(0, 0);
  STAGE(1, 1);
  asm volatile("s_waitcnt vmcnt(8)" ::: "memory");
  __builtin_amdgcn_s_barrier();
  FENCE();

  for (int kt = 0; kt < 8; ++kt) {
    const int cur = kt & 1;
    const __hip_bfloat16* As = &SB[cur][0];
    const __hip_bfloat16* Bs = &SB[cur][8192];
    __builtin_amdgcn_s_setprio(1);
#pragma unroll
    for (int kk = 0; kk < 2; ++kk) {
      const int rs = kk ? rs1 : rs0;
      short8 a[4], b[4];
#pragma unroll
      for (int i = 0; i < 4; i++)
        a[i] = *(const short8*)(As + (wr * 64 + i * 16 + (lane & 15)) * 64 + rs);
#pragma unroll
      for (int j = 0; j < 4; j++)
        b[j] = *(const short8*)(Bs + (wc * 64 + j * 16 + (lane & 15)) * 64 + rs);
#pragma unroll
      for (int i = 0; i < 4; i++)
#pragma unroll
        for (int j = 0; j < 4; j++)
          acc[i][j] = __builtin_amdgcn_mfma_f32_16x16x32_bf16(a[i], b[j], acc[i][j], 0, 0, 0);
    }
    __builtin_amdgcn_s_setprio(0);

    if (kt < 7) {
      __builtin_amdgcn_s_barrier();
      FENCE();
      if (kt + 2 < 8) {
        STAGE(cur, kt + 2);
        asm volatile("s_waitcnt vmcnt(8)" ::: "memory");
      } else {
        asm volatile("s_waitcnt vmcnt(0)" ::: "memory");
      }
      __builtin_amdgcn_s_barrier();
      FENCE();
    }
  }

#pragma unroll
  for (int i = 0; i < 4; i++) {
    const int row0 = brow + wr * 64 + i * 16 + (lane >> 4) * 4;
#pragma unroll
    for (int j = 0; j < 4; j++) {
      const int col = bcol + wc * 64 + j * 16 + (lane & 15);
#pragma unroll
      for (int r = 0; r < 4; r++) {
        float v = acc[i][j][r];
        if (OUT_F32)
          ((float*)Cg + za * sC)[(size_t)(row0 + r) * 512 + col] = v;
        else
          ((__hip_bfloat16*)Cg + za * sC)[(size_t)(row0 + r) * 512 + col] = __float2bfloat16(v);
      }
    }
  }
}

// ---- named instantiations ----
__global__ __launch_bounds__(512, 2)
void g256_h1(const __hip_bfloat16* A, const __hip_bfloat16* B, const float* bias, void* C) {
  gemm256_body<true, false, 1>(A, B, bias, C, 0, 0, 0);
}
__global__ __launch_bounds__(512, 2)
void g256_w1(const __hip_bfloat16* A, const __hip_bfloat16* B, const float* bias, void* C) {
  gemm256_body<true, false, 1>(A, B, bias, C, 0, 0, 0);
}
__global__ __launch_bounds__(512, 2)
void g256_h2(const __hip_bfloat16* A, const __hip_bfloat16* B, const float* bias, void* C) {
  gemm256_body<true, false, 1>(A, B, bias, C, 0, 0, 0);
}
__global__ __launch_bounds__(512, 2)
void g256_w2(const __hip_bfloat16* A, const __hip_bfloat16* B, const float* bias, void* C) {
  gemm256_body<true, false, 1>(A, B, bias, C, 0, 0, 0);
}
__global__ __launch_bounds__(256, 2)
void g128_p(const __hip_bfloat16* A, const __hip_bfloat16* B, void* C) {
  gemm128_body<false, 2>(A, B, C, 262144, 262144, 262144);
}
__global__ __launch_bounds__(256, 2)
void g128_y(const __hip_bfloat16* A, const __hip_bfloat16* B, void* C) {
  gemm128_body<true, 1>(A, B, C, 4096L * 512, 262144, 4096L * 512);
}

// in-place GELU over bf16 buffer, 8 elems/thread
__global__ __launch_bounds__(256)
void gelu_inplace(__hip_bfloat16* __restrict__ H, long n) {
  long i = ((long)blockIdx.x * 256 + threadIdx.x) * 8;
  if (i >= n) return;
  short8 v = *(const short8*)(H + i);
  short8 o;
#pragma unroll
  for (int j = 0; j < 8; j++) {
    float x = __bfloat162float(((const __hip_bfloat16*)&v)[j]);
    ((__hip_bfloat16*)&o)[j] = __float2bfloat16(gelu_fast(x));
  }
  *(short8*)(H + i) = o;
}

// fused fp32->bf16 for the four 512x512 weights (one launch)
__global__ __launch_bounds__(256)
void cvt_w4(const float* __restrict__ w0, const float* __restrict__ w1,
            const float* __restrict__ w2, const float* __restrict__ w3,
            __hip_bfloat16* __restrict__ o0, __hip_bfloat16* __restrict__ o1,
            __hip_bfloat16* __restrict__ o2, __hip_bfloat16* __restrict__ o3) {
  const int sel = blockIdx.x >> 7;           // 128 blocks per weight
  const float* in = sel == 0 ? w0 : sel == 1 ? w1 : sel == 2 ? w2 : w3;
  __hip_bfloat16* out = sel == 0 ? o0 : sel == 1 ? o1 : sel == 2 ? o2 : o3;
  const long i = (((long)(blockIdx.x & 127)) * 256 + threadIdx.x) * 8;
  float4 v0 = *(const float4*)(in + i);
  float4 v1 = *(const float4*)(in + i + 4);
  short8 o;
  __hip_bfloat16* ob = (__hip_bfloat16*)&o;
  ob[0] = __float2bfloat16(v0.x); ob[1] = __float2bfloat16(v0.y);
  ob[2] = __float2bfloat16(v0.z); ob[3] = __float2bfloat16(v0.w);
  ob[4] = __float2bfloat16(v1.x); ob[5] = __float2bfloat16(v1.y);
  ob[6] = __float2bfloat16(v1.z); ob[7] = __float2bfloat16(v1.w);
  *(short8*)(out + i) = o;
}

// X fp32 [B][4096][512] -> Xb bf16 + XTc bf16 [B*8][512 d][512 n]
__global__ __launch_bounds__(256)
void cvt_x_xt(const float* __restrict__ X,
              __hip_bfloat16* __restrict__ Xb,
              __hip_bfloat16* __restrict__ XT)
{
  __shared__ __hip_bfloat16 t[64][66];
  const int b  = blockIdx.z;
  const int n0 = blockIdx.y * 64;
  const int d0 = blockIdx.x * 64;
  const float* I = X + (size_t)b * 4096 * 512;
  __hip_bfloat16* XB = Xb + (size_t)b * 4096 * 512;
  __hip_bfloat16* XO = XT + ((size_t)b * 8 + (n0 >> 9)) * 512 * 512;
  const int nl0 = n0 & 511;
  const int tid = threadIdx.x;
#pragma unroll
  for (int it = 0; it < 4; ++it) {
    const int idx = it * 256 + tid;
    const int r   = idx >> 4;
    const int c4  = (idx & 15) * 4;
    float4 v = *(const float4*)&I[(size_t)(n0 + r) * 512 + d0 + c4];
    short4v o;
    __hip_bfloat16* ob = (__hip_bfloat16*)&o;
    ob[0] = __float2bfloat16(v.x); ob[1] = __float2bfloat16(v.y);
    ob[2] = __float2bfloat16(v.z); ob[3] = __float2bfloat16(v.w);
    t[r][c4]     = ob[0]; t[r][c4 + 1] = ob[1];
    t[r][c4 + 2] = ob[2]; t[r][c4 + 3] = ob[3];
    *(short4v*)&XB[(size_t)(n0 + r) * 512 + d0 + c4] = o;
  }
  __syncthreads();
#pragma unroll
  for (int it = 0; it < 4; ++it) {
    const int idx = it * 256 + tid;
    const int dr  = idx >> 4;
    const int n4  = (idx & 15) * 4;
    short4v o;
    __hip_bfloat16* ob = (__hip_bfloat16*)&o;
#pragma unroll
    for (int j = 0; j < 4; j++) ob[j] = t[n4 + j][dr];
    *(short4v*)&XO[(size_t)(d0 + dr) * 512 + nl0 + n4] = o;
  }
}

// W1n [32768 n][512 p] bf16 -> W1Tc [64 chunks][512 p][512 n-local]
__global__ __launch_bounds__(256)
void transpose_w1(const __hip_bfloat16* __restrict__ in,
                  __hip_bfloat16* __restrict__ out)
{
  __shared__ __hip_bfloat16 t[64][66];
  const int b  = blockIdx.z;
  const int n0 = blockIdx.y * 64;
  const int p0 = blockIdx.x * 64;
  const __hip_bfloat16* I = in + (size_t)b * 4096 * 512;
  __hip_bfloat16* O = out + ((size_t)b * 8 + (n0 >> 9)) * 512 * 512;
  const int nl0 = n0 & 511;
  const int tid = threadIdx.x;
#pragma unroll
  for (int it = 0; it < 2; ++it) {
    const int idx = it * 256 + tid;
    const int r   = idx >> 3;
    const int c8  = (idx & 7) * 8;
    short8 v = *(const short8*)&I[(size_t)(n0 + r) * 512 + p0 + c8];
#pragma unroll
    for (int j = 0; j < 8; j++) t[r][c8 + j] = ((const __hip_bfloat16*)&v)[j];
  }
  __syncthreads();
#pragma unroll
  for (int it = 0; it < 2; ++it) {
    const int idx = it * 256 + tid;
    const int dr  = idx >> 3;
    const int n8  = (idx & 7) * 8;
    short8 o;
#pragma unroll
    for (int j = 0; j < 8; j++) ((__hip_bfloat16*)&o)[j] = t[n8 + j][dr];
    *(short8*)&O[(size_t)(p0 + dr) * 512 + nl0 + n8] = o;
  }
}

// AT[b][i] = bf16(GELU(sum_kc part[(b*8+kc)][i]))
__global__ __launch_bounds__(256)
void reduce_gelu_bf16(const __hip_bfloat16* __restrict__ part,
                      __hip_bfloat16* __restrict__ AT) {
  const long o = ((long)blockIdx.x * 256 + threadIdx.x) * 8;
  const long b = o >> 18;
  const long i = o & 262143;
  float s[8] = {0.f, 0.f, 0.f, 0.f, 0.f, 0.f, 0.f, 0.f};
#pragma unroll
  for (int kc = 0; kc < 8; kc++) {
    short8 v = *(const short8*)(part + (((b << 3) + kc) << 18) + i);
#pragma unroll
    for (int j = 0; j < 8; j++) s[j] += __bfloat162float(((const __hip_bfloat16*)&v)[j]);
  }
  short8 o8;
#pragma unroll
  for (int j = 0; j < 8; j++)
    ((__hip_bfloat16*)&o8)[j] = __float2bfloat16(gelu_fast(s[j]));
  *(short8*)(AT + o) = o8;
}

extern "C" void kernel_launch(void* const* d_in, const int* in_sizes, int n_in,
                              void* d_out, int out_size, void* d_ws, size_t ws_size,
                              hipStream_t stream) {
  const float* X   = (const float*)d_in[0];
  const float* W1a = (const float*)d_in[1];
  const float* b1a = (const float*)d_in[2];
  const float* W1b = (const float*)d_in[3];
  const float* b1b = (const float*)d_in[4];
  const float* W2a = (const float*)d_in[5];
  const float* b2a = (const float*)d_in[6];
  const float* W2b = (const float*)d_in[7];
  const float* b2b = (const float*)d_in[8];
  float* Y = (float*)d_out;

  char* ws = (char*)d_ws;
  const size_t SZ = 33554432;  // 32768*512*2 B
  // region 0: Xb -> (after h2) W1Tc -> (after P) W2m
  // region 1: H (H1, then H2)
  // region 2: W1n -> (after transpose) part
  // region 3: XTc
  __hip_bfloat16* R0 = (__hip_bfloat16*)(ws);
  __hip_bfloat16* R1 = (__hip_bfloat16*)(ws + SZ);
  __hip_bfloat16* R2 = (__hip_bfloat16*)(ws + 2 * SZ);
  __hip_bfloat16* R3 = (__hip_bfloat16*)(ws + 3 * SZ);
  __hip_bfloat16* AT = (__hip_bfloat16*)(ws + 4 * SZ);           // 4MB
  __hip_bfloat16* Wb = (__hip_bfloat16*)(ws + 4 * SZ + 4194304); // 2MB
  __hip_bfloat16* W1ab = Wb;
  __hip_bfloat16* W1bb = Wb + 262144;
  __hip_bfloat16* W2ab = Wb + 2 * 262144;
  __hip_bfloat16* W2bb = Wb + 3 * 262144;

  dim3 blk(256), blk512(512);

  // 0) conversions; X also emits chunked XTc
  cvt_w4<<<512, blk, 0, stream>>>(W1a, W1b, W2a, W2b, W1ab, W1bb, W2ab, W2bb);
  __hip_bfloat16* Xb  = R0;
  __hip_bfloat16* XTc = R3;
  cvt_x_xt<<<dim3(8, 64, 8), blk, 0, stream>>>(X, Xb, XTc);

  // 1) H1 = Xb @ W1a^T + b1a ; GELU separate
  __hip_bfloat16* H = R1;
  g256_h1<<<dim3(2, 128, 1), blk512, 0, stream>>>(Xb, W1ab, b1a, H);
  gelu_inplace<<<8192, blk, 0, stream>>>(H, 16777216L);
  // 2) W1n = H1 @ W1b^T + b1b (natural layout)
  __hip_bfloat16* W1n = R2;
  g256_w1<<<dim3(2, 128, 1), blk512, 0, stream>>>(H, W1bb, b1b, W1n);
  // 3) H2 = Xb @ W2a^T + b2a ; GELU separate  (Xb dead after)
  g256_h2<<<dim3(2, 128, 1), blk512, 0, stream>>>(Xb, W2ab, b2a, H);
  gelu_inplace<<<8192, blk, 0, stream>>>(H, 16777216L);
  // 4) W1Tc = chunk-transpose(W1n) -> region 0 (Xb dead); W1n dead after
  __hip_bfloat16* W1Tc = R0;
  transpose_w1<<<dim3(8, 64, 8), blk, 0, stream>>>(W1n, W1Tc);
  // 5) P partials: part[z] = XTc[z] @ W1Tc[z]^T -> region 2 (W1n dead), 128^2 2blk/CU
  __hip_bfloat16* part = R2;
  g128_p<<<dim3(4, 4, 64), blk, 0, stream>>>(XTc, W1Tc, part);
  // 6) AT = GELU(sum_kc part)
  reduce_gelu_bf16<<<1024, blk, 0, stream>>>(part, AT);
  // 7) W2m = H2 @ W2b^T + b2b -> region 0 (W1Tc dead after P)
  __hip_bfloat16* W2m = R0;
  g256_w2<<<dim3(2, 128, 1), blk512, 0, stream>>>(H, W2bb, b2b, W2m);
  // 8) Y = W2m @ AT^T per batch -> fp32, 128^2 2blk/CU (store overlap)
  g128_y<<<dim3(4, 32, 8), blk, 0, stream>>>(W2m, AT, Y);
}

// Round 18
// 210.169 us; speedup vs baseline: 1.1980x; 1.0163x over previous
//
#include <hip/hip_runtime.h>
#include <hip/hip_bf16.h>

typedef __attribute__((ext_vector_type(8))) short short8;
typedef __attribute__((ext_vector_type(4))) short short4v;
typedef __attribute__((ext_vector_type(4))) float floatx4;

__device__ __forceinline__ void gload_lds16(const void* g, void* l) {
  __builtin_amdgcn_global_load_lds(
      (const __attribute__((address_space(1))) void*)g,
      (__attribute__((address_space(3))) void*)l, 16, 0, 0);
}

// tanh-approx GELU via sigmoid; branch-free (v_exp + v_rcp)
__device__ __forceinline__ float gelu_fast(float x) {
  float z = 1.5957691216f * (x + 0.044715f * x * x * x);
  float e = __expf(-z);
  return x * __builtin_amdgcn_rcpf(1.0f + e);
}

#define FENCE() asm volatile("" ::: "memory")

// ================= 256x256x(K=512) T3 2-phase NT GEMM =================
// C[M,512] = epi(A[M,512] @ B[512,512]^T + bias); 512 thr (8 waves, 2x4),
// per-wave out 128x64, BK=64, dbuf LDS 128KB.
// T3 recipe (catalog): STAGE(next) BEFORE compute(cur); ONE vmcnt(0)+barrier
// per K-step. GELU-in-epilogue BANNED (R14 A/B: +32us pathology).
template<bool HASBIAS, bool OUT_F32, int SWZ>
__device__ __forceinline__
void gemm256_body(const __hip_bfloat16* __restrict__ Ag,
                  const __hip_bfloat16* __restrict__ Bg,
                  const float* __restrict__ bias,
                  void* __restrict__ Cg,
                  long sA, long sB, long sC)
{
  int bx, by, bz;
  {
    const int gx = gridDim.x, gy = gridDim.y;
    const int f = blockIdx.x + gx * (blockIdx.y + gy * blockIdx.z);
    const int l = (f & 7) * 32 + (f >> 3);          // total == 256
    bx = l % gx;
    const int rr = l / gx;
    by = rr % gy;
    bz = rr / gy;
  }
  const long za = bz;
  const __hip_bfloat16* A = Ag + za * sA;
  const __hip_bfloat16* B = Bg + za * sB;

  __shared__ __align__(16) __hip_bfloat16 SB[2][2 * 256 * 64];  // 128KB

  const int tid  = threadIdx.x;
  const int lane = tid & 63;
  const int wid  = tid >> 6;
  const int wr   = wid >> 2;
  const int wc   = wid & 3;
  const int brow = by * 256;
  const int bcol = bx * 256;

  floatx4 acc[8][4];
#pragma unroll
  for (int i = 0; i < 8; i++)
#pragma unroll
    for (int j = 0; j < 4; j++) acc[i][j] = (floatx4){0.f, 0.f, 0.f, 0.f};

  const int srow  = tid >> 3;
  const int skoff = (((tid & 7) ^ (srow & 7))) * 8;

  auto STAGE = [&](int buf, int kt) {
    const int k0 = kt * 64;
#pragma unroll
    for (int r = 0; r < 4; ++r) {
      gload_lds16(A + (size_t)(brow + r * 64 + srow) * 512 + k0 + skoff,
                  (void*)(&SB[buf][0] + r * 4096 + tid * 8));
      gload_lds16(B + (size_t)(bcol + r * 64 + srow) * 512 + k0 + skoff,
                  (void*)(&SB[buf][16384] + r * 4096 + tid * 8));
    }
  };

  const int rs0 = (((lane >> 4)) ^ (lane & 7)) * 8;
  const int rs1 = ((4 + (lane >> 4)) ^ (lane & 7)) * 8;

  // prologue: tile 0 only; full-latency hit once
  STAGE(0, 0);
  asm volatile("s_waitcnt vmcnt(0)" ::: "memory");
  __builtin_amdgcn_s_barrier();
  FENCE();

  for (int kt = 0; kt < 8; ++kt) {
    const int cur = kt & 1;
    if (kt < 7) STAGE(cur ^ 1, kt + 1);   // next-tile loads fly UNDER compute
    const __hip_bfloat16* As = &SB[cur][0];
    const __hip_bfloat16* Bs = &SB[cur][16384];
    __builtin_amdgcn_s_setprio(1);
#pragma unroll
    for (int kk = 0; kk < 2; ++kk) {
      const int rs = kk ? rs1 : rs0;
      short8 a[8], b[4];
#pragma unroll
      for (int i = 0; i < 8; i++)
        a[i] = *(const short8*)(As + (wr * 128 + i * 16 + (lane & 15)) * 64 + rs);
#pragma unroll
      for (int j = 0; j < 4; j++)
        b[j] = *(const short8*)(Bs + (wc * 64 + j * 16 + (lane & 15)) * 64 + rs);
#pragma unroll
      for (int i = 0; i < 8; i++)
#pragma unroll
        for (int j = 0; j < 4; j++)
          acc[i][j] = __builtin_amdgcn_mfma_f32_16x16x32_bf16(a[i], b[j], acc[i][j], 0, 0, 0);
    }
    __builtin_amdgcn_s_setprio(0);

    if (kt < 7) {
      // single drain+barrier per tile: next tile landed; cur buf free
      asm volatile("s_waitcnt vmcnt(0)" ::: "memory");
      __builtin_amdgcn_s_barrier();
      FENCE();
    }
  }

  // epilogue: C/D layout col=lane&15, row=(lane>>4)*4+reg
#pragma unroll
  for (int i = 0; i < 8; i++) {
    const int row0 = brow + wr * 128 + i * 16 + (lane >> 4) * 4;
#pragma unroll
    for (int j = 0; j < 4; j++) {
      const int col = bcol + wc * 64 + j * 16 + (lane & 15);
      const float bv = HASBIAS ? bias[col] : 0.f;
#pragma unroll
      for (int r = 0; r < 4; r++) {
        float v = acc[i][j][r] + bv;
        if (OUT_F32)
          ((float*)Cg + za * sC)[(size_t)(row0 + r) * 512 + col] = v;
        else
          ((__hip_bfloat16*)Cg + za * sC)[(size_t)(row0 + r) * 512 + col] = __float2bfloat16(v);
      }
    }
  }
}

// ================= 128x128x(K=512) T3 2-phase NT GEMM =================
// 256 thr (4 waves 2x2), dbuf LDS 64KB -> 2 blk/CU. Same T3 recipe.
// SWZ=1: chunked XCD (grid total 1024). SWZ=2: P-grid (4,4,64).
template<bool OUT_F32, int SWZ>
__device__ __forceinline__
void gemm128_body(const __hip_bfloat16* __restrict__ Ag,
                  const __hip_bfloat16* __restrict__ Bg,
                  void* __restrict__ Cg,
                  long sA, long sB, long sC)
{
  int bx, by, bz;
  if (SWZ == 1) {
    const int gx = gridDim.x, gy = gridDim.y;
    const int f = blockIdx.x + gx * (blockIdx.y + gy * blockIdx.z);
    const int total = gx * gy * gridDim.z;          // 1024
    const int l = (f & 7) * (total >> 3) + (f >> 3);
    bx = l % gx;
    const int rr = l / gx;
    by = rr % gy;
    bz = rr / gy;
  } else {  // grid (4,4,64)
    const int f = blockIdx.x + 4 * (blockIdx.y + 4 * blockIdx.z);
    const int xcd = f & 7, s = f >> 3;              // s: 0..127
    bz = xcd + 8 * (s >> 4);
    const int t = s & 15;
    by = t >> 2;
    bx = t & 3;
  }
  const long za = bz;
  const __hip_bfloat16* A = Ag + za * sA;
  const __hip_bfloat16* B = Bg + za * sB;

  __shared__ __align__(16) __hip_bfloat16 SB[2][2 * 128 * 64];  // 64KB

  const int tid  = threadIdx.x;
  const int lane = tid & 63;
  const int wid  = tid >> 6;   // 0..3
  const int wr   = wid >> 1;   // 0..1
  const int wc   = wid & 1;    // 0..1
  const int brow = by * 128;
  const int bcol = bx * 128;

  floatx4 acc[4][4];
#pragma unroll
  for (int i = 0; i < 4; i++)
#pragma unroll
    for (int j = 0; j < 4; j++) acc[i][j] = (floatx4){0.f, 0.f, 0.f, 0.f};

  const int srow  = tid >> 3;                       // 0..31
  const int skoff = (((tid & 7) ^ (srow & 7))) * 8;

  auto STAGE = [&](int buf, int kt) {
    const int k0 = kt * 64;
#pragma unroll
    for (int r = 0; r < 4; ++r) {
      gload_lds16(A + (size_t)(brow + r * 32 + srow) * 512 + k0 + skoff,
                  (void*)(&SB[buf][0] + r * 2048 + tid * 8));
      gload_lds16(B + (size_t)(bcol + r * 32 + srow) * 512 + k0 + skoff,
                  (void*)(&SB[buf][8192] + r * 2048 + tid * 8));
    }
  };

  const int rs0 = (((lane >> 4)) ^ (lane & 7)) * 8;
  const int rs1 = ((4 + (lane >> 4)) ^ (lane & 7)) * 8;

  STAGE(0, 0);
  asm volatile("s_waitcnt vmcnt(0)" ::: "memory");
  __builtin_amdgcn_s_barrier();
  FENCE();

  for (int kt = 0; kt < 8; ++kt) {
    const int cur = kt & 1;
    if (kt < 7) STAGE(cur ^ 1, kt + 1);
    const __hip_bfloat16* As = &SB[cur][0];
    const __hip_bfloat16* Bs = &SB[cur][8192];
    __builtin_amdgcn_s_setprio(1);
#pragma unroll
    for (int kk = 0; kk < 2; ++kk) {
      const int rs = kk ? rs1 : rs0;
      short8 a[4], b[4];
#pragma unroll
      for (int i = 0; i < 4; i++)
        a[i] = *(const short8*)(As + (wr * 64 + i * 16 + (lane & 15)) * 64 + rs);
#pragma unroll
      for (int j = 0; j < 4; j++)
        b[j] = *(const short8*)(Bs + (wc * 64 + j * 16 + (lane & 15)) * 64 + rs);
#pragma unroll
      for (int i = 0; i < 4; i++)
#pragma unroll
        for (int j = 0; j < 4; j++)
          acc[i][j] = __builtin_amdgcn_mfma_f32_16x16x32_bf16(a[i], b[j], acc[i][j], 0, 0, 0);
    }
    __builtin_amdgcn_s_setprio(0);

    if (kt < 7) {
      asm volatile("s_waitcnt vmcnt(0)" ::: "memory");
      __builtin_amdgcn_s_barrier();
      FENCE();
    }
  }

#pragma unroll
  for (int i = 0; i < 4; i++) {
    const int row0 = brow + wr * 64 + i * 16 + (lane >> 4) * 4;
#pragma unroll
    for (int j = 0; j < 4; j++) {
      const int col = bcol + wc * 64 + j * 16 + (lane & 15);
#pragma unroll
      for (int r = 0; r < 4; r++) {
        float v = acc[i][j][r];
        if (OUT_F32)
          ((float*)Cg + za * sC)[(size_t)(row0 + r) * 512 + col] = v;
        else
          ((__hip_bfloat16*)Cg + za * sC)[(size_t)(row0 + r) * 512 + col] = __float2bfloat16(v);
      }
    }
  }
}

// ---- named instantiations ----
__global__ __launch_bounds__(512, 2)
void g256_h1(const __hip_bfloat16* A, const __hip_bfloat16* B, const float* bias, void* C) {
  gemm256_body<true, false, 1>(A, B, bias, C, 0, 0, 0);
}
__global__ __launch_bounds__(512, 2)
void g256_w1(const __hip_bfloat16* A, const __hip_bfloat16* B, const float* bias, void* C) {
  gemm256_body<true, false, 1>(A, B, bias, C, 0, 0, 0);
}
__global__ __launch_bounds__(512, 2)
void g256_h2(const __hip_bfloat16* A, const __hip_bfloat16* B, const float* bias, void* C) {
  gemm256_body<true, false, 1>(A, B, bias, C, 0, 0, 0);
}
__global__ __launch_bounds__(512, 2)
void g256_w2(const __hip_bfloat16* A, const __hip_bfloat16* B, const float* bias, void* C) {
  gemm256_body<true, false, 1>(A, B, bias, C, 0, 0, 0);
}
__global__ __launch_bounds__(256, 2)
void g128_p(const __hip_bfloat16* A, const __hip_bfloat16* B, void* C) {
  gemm128_body<false, 2>(A, B, C, 262144, 262144, 262144);
}
__global__ __launch_bounds__(256, 2)
void g128_y(const __hip_bfloat16* A, const __hip_bfloat16* B, void* C) {
  gemm128_body<true, 1>(A, B, C, 4096L * 512, 262144, 4096L * 512);
}

// in-place GELU over bf16 buffer, 8 elems/thread
__global__ __launch_bounds__(256)
void gelu_inplace(__hip_bfloat16* __restrict__ H, long n) {
  long i = ((long)blockIdx.x * 256 + threadIdx.x) * 8;
  if (i >= n) return;
  short8 v = *(const short8*)(H + i);
  short8 o;
#pragma unroll
  for (int j = 0; j < 8; j++) {
    float x = __bfloat162float(((const __hip_bfloat16*)&v)[j]);
    ((__hip_bfloat16*)&o)[j] = __float2bfloat16(gelu_fast(x));
  }
  *(short8*)(H + i) = o;
}

// fused fp32->bf16 for the four 512x512 weights (one launch)
__global__ __launch_bounds__(256)
void cvt_w4(const float* __restrict__ w0, const float* __restrict__ w1,
            const float* __restrict__ w2, const float* __restrict__ w3,
            __hip_bfloat16* __restrict__ o0, __hip_bfloat16* __restrict__ o1,
            __hip_bfloat16* __restrict__ o2, __hip_bfloat16* __restrict__ o3) {
  const int sel = blockIdx.x >> 7;           // 128 blocks per weight
  const float* in = sel == 0 ? w0 : sel == 1 ? w1 : sel == 2 ? w2 : w3;
  __hip_bfloat16* out = sel == 0 ? o0 : sel == 1 ? o1 : sel == 2 ? o2 : o3;
  const long i = (((long)(blockIdx.x & 127)) * 256 + threadIdx.x) * 8;
  float4 v0 = *(const float4*)(in + i);
  float4 v1 = *(const float4*)(in + i + 4);
  short8 o;
  __hip_bfloat16* ob = (__hip_bfloat16*)&o;
  ob[0] = __float2bfloat16(v0.x); ob[1] = __float2bfloat16(v0.y);
  ob[2] = __float2bfloat16(v0.z); ob[3] = __float2bfloat16(v0.w);
  ob[4] = __float2bfloat16(v1.x); ob[5] = __float2bfloat16(v1.y);
  ob[6] = __float2bfloat16(v1.z); ob[7] = __float2bfloat16(v1.w);
  *(short8*)(out + i) = o;
}

// X fp32 [B][4096][512] -> Xb bf16 + XTc bf16 [B*8][512 d][512 n]
__global__ __launch_bounds__(256)
void cvt_x_xt(const float* __restrict__ X,
              __hip_bfloat16* __restrict__ Xb,
              __hip_bfloat16* __restrict__ XT)
{
  __shared__ __hip_bfloat16 t[64][66];
  const int b  = blockIdx.z;
  const int n0 = blockIdx.y * 64;
  const int d0 = blockIdx.x * 64;
  const float* I = X + (size_t)b * 4096 * 512;
  __hip_bfloat16* XB = Xb + (size_t)b * 4096 * 512;
  __hip_bfloat16* XO = XT + ((size_t)b * 8 + (n0 >> 9)) * 512 * 512;
  const int nl0 = n0 & 511;
  const int tid = threadIdx.x;
#pragma unroll
  for (int it = 0; it < 4; ++it) {
    const int idx = it * 256 + tid;
    const int r   = idx >> 4;
    const int c4  = (idx & 15) * 4;
    float4 v = *(const float4*)&I[(size_t)(n0 + r) * 512 + d0 + c4];
    short4v o;
    __hip_bfloat16* ob = (__hip_bfloat16*)&o;
    ob[0] = __float2bfloat16(v.x); ob[1] = __float2bfloat16(v.y);
    ob[2] = __float2bfloat16(v.z); ob[3] = __float2bfloat16(v.w);
    t[r][c4]     = ob[0]; t[r][c4 + 1] = ob[1];
    t[r][c4 + 2] = ob[2]; t[r][c4 + 3] = ob[3];
    *(short4v*)&XB[(size_t)(n0 + r) * 512 + d0 + c4] = o;
  }
  __syncthreads();
#pragma unroll
  for (int it = 0; it < 4; ++it) {
    const int idx = it * 256 + tid;
    const int dr  = idx >> 4;
    const int n4  = (idx & 15) * 4;
    short4v o;
    __hip_bfloat16* ob = (__hip_bfloat16*)&o;
#pragma unroll
    for (int j = 0; j < 4; j++) ob[j] = t[n4 + j][dr];
    *(short4v*)&XO[(size_t)(d0 + dr) * 512 + nl0 + n4] = o;
  }
}

// W1n [32768 n][512 p] bf16 -> W1Tc [64 chunks][512 p][512 n-local]
__global__ __launch_bounds__(256)
void transpose_w1(const __hip_bfloat16* __restrict__ in,
                  __hip_bfloat16* __restrict__ out)
{
  __shared__ __hip_bfloat16 t[64][66];
  const int b  = blockIdx.z;
  const int n0 = blockIdx.y * 64;
  const int p0 = blockIdx.x * 64;
  const __hip_bfloat16* I = in + (size_t)b * 4096 * 512;
  __hip_bfloat16* O = out + ((size_t)b * 8 + (n0 >> 9)) * 512 * 512;
  const int nl0 = n0 & 511;
  const int tid = threadIdx.x;
#pragma unroll
  for (int it = 0; it < 2; ++it) {
    const int idx = it * 256 + tid;
    const int r   = idx >> 3;
    const int c8  = (idx & 7) * 8;
    short8 v = *(const short8*)&I[(size_t)(n0 + r) * 512 + p0 + c8];
#pragma unroll
    for (int j = 0; j < 8; j++) t[r][c8 + j] = ((const __hip_bfloat16*)&v)[j];
  }
  __syncthreads();
#pragma unroll
  for (int it = 0; it < 2; ++it) {
    const int idx = it * 256 + tid;
    const int dr  = idx >> 3;
    const int n8  = (idx & 7) * 8;
    short8 o;
#pragma unroll
    for (int j = 0; j < 8; j++) ((__hip_bfloat16*)&o)[j] = t[n8 + j][dr];
    *(short8*)&O[(size_t)(p0 + dr) * 512 + nl0 + n8] = o;
  }
}

// AT[b][i] = bf16(GELU(sum_kc part[(b*8+kc)][i]))
__global__ __launch_bounds__(256)
void reduce_gelu_bf16(const __hip_bfloat16* __restrict__ part,
                      __hip_bfloat16* __restrict__ AT) {
  const long o = ((long)blockIdx.x * 256 + threadIdx.x) * 8;
  const long b = o >> 18;
  const long i = o & 262143;
  float s[8] = {0.f, 0.f, 0.f, 0.f, 0.f, 0.f, 0.f, 0.f};
#pragma unroll
  for (int kc = 0; kc < 8; kc++) {
    short8 v = *(const short8*)(part + (((b << 3) + kc) << 18) + i);
#pragma unroll
    for (int j = 0; j < 8; j++) s[j] += __bfloat162float(((const __hip_bfloat16*)&v)[j]);
  }
  short8 o8;
#pragma unroll
  for (int j = 0; j < 8; j++)
    ((__hip_bfloat16*)&o8)[j] = __float2bfloat16(gelu_fast(s[j]));
  *(short8*)(AT + o) = o8;
}

extern "C" void kernel_launch(void* const* d_in, const int* in_sizes, int n_in,
                              void* d_out, int out_size, void* d_ws, size_t ws_size,
                              hipStream_t stream) {
  const float* X   = (const float*)d_in[0];
  const float* W1a = (const float*)d_in[1];
  const float* b1a = (const float*)d_in[2];
  const float* W1b = (const float*)d_in[3];
  const float* b1b = (const float*)d_in[4];
  const float* W2a = (const float*)d_in[5];
  const float* b2a = (const float*)d_in[6];
  const float* W2b = (const float*)d_in[7];
  const float* b2b = (const float*)d_in[8];
  float* Y = (float*)d_out;

  char* ws = (char*)d_ws;
  const size_t SZ = 33554432;  // 32768*512*2 B
  // region 0: Xb -> (after h2) W1Tc -> (after P) W2m
  // region 1: H (H1, then H2)
  // region 2: W1n -> (after transpose) part
  // region 3: XTc
  __hip_bfloat16* R0 = (__hip_bfloat16*)(ws);
  __hip_bfloat16* R1 = (__hip_bfloat16*)(ws + SZ);
  __hip_bfloat16* R2 = (__hip_bfloat16*)(ws + 2 * SZ);
  __hip_bfloat16* R3 = (__hip_bfloat16*)(ws + 3 * SZ);
  __hip_bfloat16* AT = (__hip_bfloat16*)(ws + 4 * SZ);           // 4MB
  __hip_bfloat16* Wb = (__hip_bfloat16*)(ws + 4 * SZ + 4194304); // 2MB
  __hip_bfloat16* W1ab = Wb;
  __hip_bfloat16* W1bb = Wb + 262144;
  __hip_bfloat16* W2ab = Wb + 2 * 262144;
  __hip_bfloat16* W2bb = Wb + 3 * 262144;

  dim3 blk(256), blk512(512);

  // 0) conversions; X also emits chunked XTc
  cvt_w4<<<512, blk, 0, stream>>>(W1a, W1b, W2a, W2b, W1ab, W1bb, W2ab, W2bb);
  __hip_bfloat16* Xb  = R0;
  __hip_bfloat16* XTc = R3;
  cvt_x_xt<<<dim3(8, 64, 8), blk, 0, stream>>>(X, Xb, XTc);

  // 1) H1 = Xb @ W1a^T + b1a ; GELU separate
  __hip_bfloat16* H = R1;
  g256_h1<<<dim3(2, 128, 1), blk512, 0, stream>>>(Xb, W1ab, b1a, H);
  gelu_inplace<<<8192, blk, 0, stream>>>(H, 16777216L);
  // 2) W1n = H1 @ W1b^T + b1b (natural layout)
  __hip_bfloat16* W1n = R2;
  g256_w1<<<dim3(2, 128, 1), blk512, 0, stream>>>(H, W1bb, b1b, W1n);
  // 3) H2 = Xb @ W2a^T + b2a ; GELU separate  (Xb dead after)
  g256_h2<<<dim3(2, 128, 1), blk512, 0, stream>>>(Xb, W2ab, b2a, H);
  gelu_inplace<<<8192, blk, 0, stream>>>(H, 16777216L);
  // 4) W1Tc = chunk-transpose(W1n) -> region 0 (Xb dead); W1n dead after
  __hip_bfloat16* W1Tc = R0;
  transpose_w1<<<dim3(8, 64, 8), blk, 0, stream>>>(W1n, W1Tc);
  // 5) P partials: part[z] = XTc[z] @ W1Tc[z]^T -> region 2 (W1n dead)
  __hip_bfloat16* part = R2;
  g128_p<<<dim3(4, 4, 64), blk, 0, stream>>>(XTc, W1Tc, part);
  // 6) AT = GELU(sum_kc part)
  reduce_gelu_bf16<<<1024, blk, 0, stream>>>(part, AT);
  // 7) W2m = H2 @ W2b^T + b2b -> region 0 (W1Tc dead after P)
  __hip_bfloat16* W2m = R0;
  g256_w2<<<dim3(2, 128, 1), blk512, 0, stream>>>(H, W2bb, b2b, W2m);
  // 8) Y = W2m @ AT^T per batch -> fp32, 128^2 2blk/CU
  g128_y<<<dim3(4, 32, 8), blk, 0, stream>>>(W2m, AT, Y);
}

// Round 19
// 200.440 us; speedup vs baseline: 1.2562x; 1.0485x over previous
//
#include <hip/hip_runtime.h>
#include <hip/hip_bf16.h>

typedef __attribute__((ext_vector_type(8))) short short8;
typedef __attribute__((ext_vector_type(4))) short short4v;
typedef __attribute__((ext_vector_type(4))) float floatx4;

__device__ __forceinline__ void gload_lds16(const void* g, void* l) {
  __builtin_amdgcn_global_load_lds(
      (const __attribute__((address_space(1))) void*)g,
      (__attribute__((address_space(3))) void*)l, 16, 0, 0);
}

// tanh-approx GELU via sigmoid; branch-free (v_exp + v_rcp)
__device__ __forceinline__ float gelu_fast(float x) {
  float z = 1.5957691216f * (x + 0.044715f * x * x * x);
  float e = __expf(-z);
  return x * __builtin_amdgcn_rcpf(1.0f + e);
}

#define FENCE() asm volatile("" ::: "memory")

// ================= 128x128x(K=512) T3/T4 NT GEMM =================
// 256 thr (4 waves 2x2), per-wave out 64x64, BK=64, dbuf LDS 64KB -> 2 blk/CU.
// TLP is the proven lever at K=8-steps (R16->R17 A/B: -11..14us per GEMM).
// T2 swizzle via pre-swizzled global source; STAGE-before-compute; one
// vmcnt(0)+barrier per K-step. GELU-in-epilogue BANNED (R14: +32us pathology).
// SWZ=1: chunked XCD (grid total must be divisible by 8; same-A-panel blocks
//        share an XCD at gx=4). SWZ=2: P-grid (4,4,64).
template<bool HASBIAS, bool OUT_F32, int SWZ>
__device__ __forceinline__
void gemm128_body(const __hip_bfloat16* __restrict__ Ag,
                  const __hip_bfloat16* __restrict__ Bg,
                  const float* __restrict__ bias,
                  void* __restrict__ Cg,
                  long sA, long sB, long sC)
{
  int bx, by, bz;
  if (SWZ == 1) {
    const int gx = gridDim.x, gy = gridDim.y;
    const int f = blockIdx.x + gx * (blockIdx.y + gy * blockIdx.z);
    const int total = gx * gy * gridDim.z;
    const int l = (f & 7) * (total >> 3) + (f >> 3);
    bx = l % gx;
    const int rr = l / gx;
    by = rr % gy;
    bz = rr / gy;
  } else {  // grid (4,4,64)
    const int f = blockIdx.x + 4 * (blockIdx.y + 4 * blockIdx.z);
    const int xcd = f & 7, s = f >> 3;              // s: 0..127
    bz = xcd + 8 * (s >> 4);
    const int t = s & 15;
    by = t >> 2;
    bx = t & 3;
  }
  const long za = bz;
  const __hip_bfloat16* A = Ag + za * sA;
  const __hip_bfloat16* B = Bg + za * sB;

  __shared__ __align__(16) __hip_bfloat16 SB[2][2 * 128 * 64];  // 64KB

  const int tid  = threadIdx.x;
  const int lane = tid & 63;
  const int wid  = tid >> 6;   // 0..3
  const int wr   = wid >> 1;   // 0..1
  const int wc   = wid & 1;    // 0..1
  const int brow = by * 128;
  const int bcol = bx * 128;

  floatx4 acc[4][4];
#pragma unroll
  for (int i = 0; i < 4; i++)
#pragma unroll
    for (int j = 0; j < 4; j++) acc[i][j] = (floatx4){0.f, 0.f, 0.f, 0.f};

  const int srow  = tid >> 3;                       // 0..31
  const int skoff = (((tid & 7) ^ (srow & 7))) * 8;

  auto STAGE = [&](int buf, int kt) {
    const int k0 = kt * 64;
#pragma unroll
    for (int r = 0; r < 4; ++r) {
      gload_lds16(A + (size_t)(brow + r * 32 + srow) * 512 + k0 + skoff,
                  (void*)(&SB[buf][0] + r * 2048 + tid * 8));
      gload_lds16(B + (size_t)(bcol + r * 32 + srow) * 512 + k0 + skoff,
                  (void*)(&SB[buf][8192] + r * 2048 + tid * 8));
    }
  };

  const int rs0 = (((lane >> 4)) ^ (lane & 7)) * 8;
  const int rs1 = ((4 + (lane >> 4)) ^ (lane & 7)) * 8;

  STAGE(0, 0);
  asm volatile("s_waitcnt vmcnt(0)" ::: "memory");
  __builtin_amdgcn_s_barrier();
  FENCE();

  for (int kt = 0; kt < 8; ++kt) {
    const int cur = kt & 1;
    if (kt < 7) STAGE(cur ^ 1, kt + 1);   // next-tile loads fly under compute
    const __hip_bfloat16* As = &SB[cur][0];
    const __hip_bfloat16* Bs = &SB[cur][8192];
    __builtin_amdgcn_s_setprio(1);
#pragma unroll
    for (int kk = 0; kk < 2; ++kk) {
      const int rs = kk ? rs1 : rs0;
      short8 a[4], b[4];
#pragma unroll
      for (int i = 0; i < 4; i++)
        a[i] = *(const short8*)(As + (wr * 64 + i * 16 + (lane & 15)) * 64 + rs);
#pragma unroll
      for (int j = 0; j < 4; j++)
        b[j] = *(const short8*)(Bs + (wc * 64 + j * 16 + (lane & 15)) * 64 + rs);
#pragma unroll
      for (int i = 0; i < 4; i++)
#pragma unroll
        for (int j = 0; j < 4; j++)
          acc[i][j] = __builtin_amdgcn_mfma_f32_16x16x32_bf16(a[i], b[j], acc[i][j], 0, 0, 0);
    }
    __builtin_amdgcn_s_setprio(0);

    if (kt < 7) {
      asm volatile("s_waitcnt vmcnt(0)" ::: "memory");
      __builtin_amdgcn_s_barrier();
      FENCE();
    }
  }

  // epilogue: C/D layout col=lane&15, row=(lane>>4)*4+reg
#pragma unroll
  for (int i = 0; i < 4; i++) {
    const int row0 = brow + wr * 64 + i * 16 + (lane >> 4) * 4;
#pragma unroll
    for (int j = 0; j < 4; j++) {
      const int col = bcol + wc * 64 + j * 16 + (lane & 15);
      const float bv = HASBIAS ? bias[col] : 0.f;
#pragma unroll
      for (int r = 0; r < 4; r++) {
        float v = acc[i][j][r] + bv;
        if (OUT_F32)
          ((float*)Cg + za * sC)[(size_t)(row0 + r) * 512 + col] = v;
        else
          ((__hip_bfloat16*)Cg + za * sC)[(size_t)(row0 + r) * 512 + col] = __float2bfloat16(v);
      }
    }
  }
}

// ---- named instantiations (all 128^2, 2 blk/CU) ----
__global__ __launch_bounds__(256, 2)
void g128_h1(const __hip_bfloat16* A, const __hip_bfloat16* B, const float* bias, void* C) {
  gemm128_body<true, false, 1>(A, B, bias, C, 0, 0, 0);
}
__global__ __launch_bounds__(256, 2)
void g128_w1(const __hip_bfloat16* A, const __hip_bfloat16* B, const float* bias, void* C) {
  gemm128_body<true, false, 1>(A, B, bias, C, 0, 0, 0);
}
__global__ __launch_bounds__(256, 2)
void g128_h2(const __hip_bfloat16* A, const __hip_bfloat16* B, const float* bias, void* C) {
  gemm128_body<true, false, 1>(A, B, bias, C, 0, 0, 0);
}
__global__ __launch_bounds__(256, 2)
void g128_w2(const __hip_bfloat16* A, const __hip_bfloat16* B, const float* bias, void* C) {
  gemm128_body<true, false, 1>(A, B, bias, C, 0, 0, 0);
}
__global__ __launch_bounds__(256, 2)
void g128_p(const __hip_bfloat16* A, const __hip_bfloat16* B, void* C) {
  gemm128_body<false, false, 2>(A, B, nullptr, C, 262144, 262144, 262144);
}
__global__ __launch_bounds__(256, 2)
void g128_y(const __hip_bfloat16* A, const __hip_bfloat16* B, void* C) {
  gemm128_body<false, true, 1>(A, B, nullptr, C, 4096L * 512, 262144, 4096L * 512);
}

// in-place GELU over bf16 buffer, 8 elems/thread
__global__ __launch_bounds__(256)
void gelu_inplace(__hip_bfloat16* __restrict__ H, long n) {
  long i = ((long)blockIdx.x * 256 + threadIdx.x) * 8;
  if (i >= n) return;
  short8 v = *(const short8*)(H + i);
  short8 o;
#pragma unroll
  for (int j = 0; j < 8; j++) {
    float x = __bfloat162float(((const __hip_bfloat16*)&v)[j]);
    ((__hip_bfloat16*)&o)[j] = __float2bfloat16(gelu_fast(x));
  }
  *(short8*)(H + i) = o;
}

// fused fp32->bf16 for the four 512x512 weights (one launch)
__global__ __launch_bounds__(256)
void cvt_w4(const float* __restrict__ w0, const float* __restrict__ w1,
            const float* __restrict__ w2, const float* __restrict__ w3,
            __hip_bfloat16* __restrict__ o0, __hip_bfloat16* __restrict__ o1,
            __hip_bfloat16* __restrict__ o2, __hip_bfloat16* __restrict__ o3) {
  const int sel = blockIdx.x >> 7;           // 128 blocks per weight
  const float* in = sel == 0 ? w0 : sel == 1 ? w1 : sel == 2 ? w2 : w3;
  __hip_bfloat16* out = sel == 0 ? o0 : sel == 1 ? o1 : sel == 2 ? o2 : o3;
  const long i = (((long)(blockIdx.x & 127)) * 256 + threadIdx.x) * 8;
  float4 v0 = *(const float4*)(in + i);
  float4 v1 = *(const float4*)(in + i + 4);
  short8 o;
  __hip_bfloat16* ob = (__hip_bfloat16*)&o;
  ob[0] = __float2bfloat16(v0.x); ob[1] = __float2bfloat16(v0.y);
  ob[2] = __float2bfloat16(v0.z); ob[3] = __float2bfloat16(v0.w);
  ob[4] = __float2bfloat16(v1.x); ob[5] = __float2bfloat16(v1.y);
  ob[6] = __float2bfloat16(v1.z); ob[7] = __float2bfloat16(v1.w);
  *(short8*)(out + i) = o;
}

// X fp32 [B][4096][512] -> Xb bf16 + XTc bf16 [B*8][512 d][512 n]
__global__ __launch_bounds__(256)
void cvt_x_xt(const float* __restrict__ X,
              __hip_bfloat16* __restrict__ Xb,
              __hip_bfloat16* __restrict__ XT)
{
  __shared__ __hip_bfloat16 t[64][66];
  const int b  = blockIdx.z;
  const int n0 = blockIdx.y * 64;
  const int d0 = blockIdx.x * 64;
  const float* I = X + (size_t)b * 4096 * 512;
  __hip_bfloat16* XB = Xb + (size_t)b * 4096 * 512;
  __hip_bfloat16* XO = XT + ((size_t)b * 8 + (n0 >> 9)) * 512 * 512;
  const int nl0 = n0 & 511;
  const int tid = threadIdx.x;
#pragma unroll
  for (int it = 0; it < 4; ++it) {
    const int idx = it * 256 + tid;
    const int r   = idx >> 4;
    const int c4  = (idx & 15) * 4;
    float4 v = *(const float4*)&I[(size_t)(n0 + r) * 512 + d0 + c4];
    short4v o;
    __hip_bfloat16* ob = (__hip_bfloat16*)&o;
    ob[0] = __float2bfloat16(v.x); ob[1] = __float2bfloat16(v.y);
    ob[2] = __float2bfloat16(v.z); ob[3] = __float2bfloat16(v.w);
    t[r][c4]     = ob[0]; t[r][c4 + 1] = ob[1];
    t[r][c4 + 2] = ob[2]; t[r][c4 + 3] = ob[3];
    *(short4v*)&XB[(size_t)(n0 + r) * 512 + d0 + c4] = o;
  }
  __syncthreads();
#pragma unroll
  for (int it = 0; it < 4; ++it) {
    const int idx = it * 256 + tid;
    const int dr  = idx >> 4;
    const int n4  = (idx & 15) * 4;
    short4v o;
    __hip_bfloat16* ob = (__hip_bfloat16*)&o;
#pragma unroll
    for (int j = 0; j < 4; j++) ob[j] = t[n4 + j][dr];
    *(short4v*)&XO[(size_t)(d0 + dr) * 512 + nl0 + n4] = o;
  }
}

// W1n [32768 n][512 p] bf16 -> W1Tc [64 chunks][512 p][512 n-local]
__global__ __launch_bounds__(256)
void transpose_w1(const __hip_bfloat16* __restrict__ in,
                  __hip_bfloat16* __restrict__ out)
{
  __shared__ __hip_bfloat16 t[64][66];
  const int b  = blockIdx.z;
  const int n0 = blockIdx.y * 64;
  const int p0 = blockIdx.x * 64;
  const __hip_bfloat16* I = in + (size_t)b * 4096 * 512;
  __hip_bfloat16* O = out + ((size_t)b * 8 + (n0 >> 9)) * 512 * 512;
  const int nl0 = n0 & 511;
  const int tid = threadIdx.x;
#pragma unroll
  for (int it = 0; it < 2; ++it) {
    const int idx = it * 256 + tid;
    const int r   = idx >> 3;
    const int c8  = (idx & 7) * 8;
    short8 v = *(const short8*)&I[(size_t)(n0 + r) * 512 + p0 + c8];
#pragma unroll
    for (int j = 0; j < 8; j++) t[r][c8 + j] = ((const __hip_bfloat16*)&v)[j];
  }
  __syncthreads();
#pragma unroll
  for (int it = 0; it < 2; ++it) {
    const int idx = it * 256 + tid;
    const int dr  = idx >> 3;
    const int n8  = (idx & 7) * 8;
    short8 o;
#pragma unroll
    for (int j = 0; j < 8; j++) ((__hip_bfloat16*)&o)[j] = t[n8 + j][dr];
    *(short8*)&O[(size_t)(p0 + dr) * 512 + nl0 + n8] = o;
  }
}

// AT[b][i] = bf16(GELU(sum_kc part[(b*8+kc)][i]))
__global__ __launch_bounds__(256)
void reduce_gelu_bf16(const __hip_bfloat16* __restrict__ part,
                      __hip_bfloat16* __restrict__ AT) {
  const long o = ((long)blockIdx.x * 256 + threadIdx.x) * 8;
  const long b = o >> 18;
  const long i = o & 262143;
  float s[8] = {0.f, 0.f, 0.f, 0.f, 0.f, 0.f, 0.f, 0.f};
#pragma unroll
  for (int kc = 0; kc < 8; kc++) {
    short8 v = *(const short8*)(part + (((b << 3) + kc) << 18) + i);
#pragma unroll
    for (int j = 0; j < 8; j++) s[j] += __bfloat162float(((const __hip_bfloat16*)&v)[j]);
  }
  short8 o8;
#pragma unroll
  for (int j = 0; j < 8; j++)
    ((__hip_bfloat16*)&o8)[j] = __float2bfloat16(gelu_fast(s[j]));
  *(short8*)(AT + o) = o8;
}

extern "C" void kernel_launch(void* const* d_in, const int* in_sizes, int n_in,
                              void* d_out, int out_size, void* d_ws, size_t ws_size,
                              hipStream_t stream) {
  const float* X   = (const float*)d_in[0];
  const float* W1a = (const float*)d_in[1];
  const float* b1a = (const float*)d_in[2];
  const float* W1b = (const float*)d_in[3];
  const float* b1b = (const float*)d_in[4];
  const float* W2a = (const float*)d_in[5];
  const float* b2a = (const float*)d_in[6];
  const float* W2b = (const float*)d_in[7];
  const float* b2b = (const float*)d_in[8];
  float* Y = (float*)d_out;

  char* ws = (char*)d_ws;
  const size_t SZ = 33554432;  // 32768*512*2 B
  // region 0: Xb -> (after h2) W1Tc -> (after P) W2m
  // region 1: H (H1, then H2)
  // region 2: W1n -> (after transpose) part
  // region 3: XTc
  __hip_bfloat16* R0 = (__hip_bfloat16*)(ws);
  __hip_bfloat16* R1 = (__hip_bfloat16*)(ws + SZ);
  __hip_bfloat16* R2 = (__hip_bfloat16*)(ws + 2 * SZ);
  __hip_bfloat16* R3 = (__hip_bfloat16*)(ws + 3 * SZ);
  __hip_bfloat16* AT = (__hip_bfloat16*)(ws + 4 * SZ);           // 4MB
  __hip_bfloat16* Wb = (__hip_bfloat16*)(ws + 4 * SZ + 4194304); // 2MB
  __hip_bfloat16* W1ab = Wb;
  __hip_bfloat16* W1bb = Wb + 262144;
  __hip_bfloat16* W2ab = Wb + 2 * 262144;
  __hip_bfloat16* W2bb = Wb + 3 * 262144;

  dim3 blk(256);

  // 0) conversions; X also emits chunked XTc
  cvt_w4<<<512, blk, 0, stream>>>(W1a, W1b, W2a, W2b, W1ab, W1bb, W2ab, W2bb);
  __hip_bfloat16* Xb  = R0;
  __hip_bfloat16* XTc = R3;
  cvt_x_xt<<<dim3(8, 64, 8), blk, 0, stream>>>(X, Xb, XTc);

  // 1) H1 = Xb @ W1a^T + b1a ; GELU separate
  __hip_bfloat16* H = R1;
  g128_h1<<<dim3(4, 256, 1), blk, 0, stream>>>(Xb, W1ab, b1a, H);
  gelu_inplace<<<8192, blk, 0, stream>>>(H, 16777216L);
  // 2) W1n = H1 @ W1b^T + b1b (natural layout)
  __hip_bfloat16* W1n = R2;
  g128_w1<<<dim3(4, 256, 1), blk, 0, stream>>>(H, W1bb, b1b, W1n);
  // 3) H2 = Xb @ W2a^T + b2a ; GELU separate  (Xb dead after)
  g128_h2<<<dim3(4, 256, 1), blk, 0, stream>>>(Xb, W2ab, b2a, H);
  gelu_inplace<<<8192, blk, 0, stream>>>(H, 16777216L);
  // 4) W1Tc = chunk-transpose(W1n) -> region 0 (Xb dead); W1n dead after
  __hip_bfloat16* W1Tc = R0;
  transpose_w1<<<dim3(8, 64, 8), blk, 0, stream>>>(W1n, W1Tc);
  // 5) P partials: part[z] = XTc[z] @ W1Tc[z]^T -> region 2 (W1n dead)
  __hip_bfloat16* part = R2;
  g128_p<<<dim3(4, 4, 64), blk, 0, stream>>>(XTc, W1Tc, part);
  // 6) AT = GELU(sum_kc part)
  reduce_gelu_bf16<<<1024, blk, 0, stream>>>(part, AT);
  // 7) W2m = H2 @ W2b^T + b2b -> region 0 (W1Tc dead after P)
  __hip_bfloat16* W2m = R0;
  g128_w2<<<dim3(4, 256, 1), blk, 0, stream>>>(H, W2bb, b2b, W2m);
  // 8) Y = W2m @ AT^T per batch -> fp32
  g128_y<<<dim3(4, 32, 8), blk, 0, stream>>>(W2m, AT, Y);
}